// Round 2
// baseline (3767.321 us; speedup 1.0000x reference)
//
#include <hip/hip_runtime.h>
#include <hip/hip_bf16.h>
#include <math.h>

typedef unsigned int  u32;
typedef unsigned short u16;
typedef unsigned char u8;

#define BTn   192
#define NQn   64
#define NCn   1024
#define Cd    384
#define Hn    8
#define DHn   48
#define HIDn  1536
#define ROWSX (BTn*NQn)     /* 12288 */
#define ROWSC (BTn*NCn)     /* 196608 */
#define ATT_SCALE 0.14433756729740643f

__device__ __forceinline__ float bf2f(u32 u) {
  union { u32 i; float f; } v; v.i = u << 16; return v.f;
}
__device__ __forceinline__ u16 f2bf(float f) {
  union { float f; u32 i; } v; v.f = f;
  u32 x = v.i;
  x += 0x7fffu + ((x >> 16) & 1u);   // round-to-nearest-even
  return (u16)(x >> 16);
}
__device__ __forceinline__ void decode8(uint4 r, float* v) {
  v[0]=bf2f(r.x & 0xffffu); v[1]=bf2f(r.x >> 16);
  v[2]=bf2f(r.y & 0xffffu); v[3]=bf2f(r.y >> 16);
  v[4]=bf2f(r.z & 0xffffu); v[5]=bf2f(r.z >> 16);
  v[6]=bf2f(r.w & 0xffffu); v[7]=bf2f(r.w >> 16);
}
__device__ __forceinline__ float gelu_tanh(float x) {
  float inner = 0.7978845608028654f * (x + 0.044715f * x * x * x);
  return 0.5f * x * (1.0f + tanhf(inner));
}

// ---------------- mask decode (robust to u8 / i32 / bf16 / f32 storage) ---
__global__ void decode_mask_kernel(const u8* __restrict__ m, u8* __restrict__ keep) {
  __shared__ int flags[3];   // 0: any byte >1 ; 1: nonzero at idx%4!=0 ; 2: nonzero at idx%4<2
  int t = threadIdx.x;
  if (t < 3) flags[t] = 0;
  __syncthreads();
  int nonbin = 0, oddset = 0, low01 = 0;
  for (int i = t; i < ROWSX; i += 256) {
    u32 b = m[i];
    if (b > 1u) nonbin = 1;
    if ((i & 3) && b) oddset = 1;
    if (((i & 3) < 2) && b) low01 = 1;
  }
  if (nonbin) flags[0] = 1;
  if (oddset) flags[1] = 1;
  if (low01)  flags[2] = 1;
  __syncthreads();
  int mode = flags[0] ? (flags[2] ? 2 : 3) : (flags[1] ? 1 : 0);
  // mode: 0 = int32, 1 = u8/bool, 2 = bf16, 3 = fp32
  for (int i = t; i < ROWSX; i += 256) {
    u8 k;
    if (mode == 2)      k = (m[2*i] | m[2*i+1]) ? 1 : 0;
    else if (mode == 3) k = (((const float*)m)[i] != 0.f) ? 1 : 0;
    else if (mode == 1) k = m[i] ? 1 : 0;
    else                k = (((const int*)m)[i] != 0) ? 1 : 0;
    keep[i] = k;
  }
}

// ---------------- per-row LayerNorm stats (mean, rstd) --------------------
template<int SRCF32>
__global__ __launch_bounds__(256) void row_stats_kernel(
    const void* __restrict__ srcv, float* __restrict__ stats, int nrows, float eps) {
  int row = blockIdx.x * 4 + (threadIdx.x >> 6);
  int lane = threadIdx.x & 63;
  if (row >= nrows) return;
  float s = 0.f, s2 = 0.f;
  if (SRCF32) {
    const float2* p2 = (const float2*)((const float*)srcv + (size_t)row * Cd);
    #pragma unroll
    for (int i = 0; i < 3; i++) {
      float2 u = p2[lane + 64*i];
      s += u.x + u.y; s2 += u.x*u.x + u.y*u.y;
    }
  } else {
    const u32* p2 = (const u32*)((const u16*)srcv + (size_t)row * Cd);
    #pragma unroll
    for (int i = 0; i < 3; i++) {
      u32 u = p2[lane + 64*i];
      float a = bf2f(u & 0xffffu), b = bf2f(u >> 16);
      s += a + b; s2 += a*a + b*b;
    }
  }
  #pragma unroll
  for (int off = 32; off >= 1; off >>= 1) {
    s  += __shfl_down(s,  off);
    s2 += __shfl_down(s2, off);
  }
  if (lane == 0) {
    float m = s * (1.0f/Cd);
    float var = s2 * (1.0f/Cd) - m*m;
    var = var > 0.f ? var : 0.f;
    stats[2*row]   = m;
    stats[2*row+1] = rsqrtf(var + eps);
  }
}

// ---------------- generic tiled GEMM: C = ep( LN(A)@B + bias [+res] ) -----
// A: [M][K] fp32 or bf16 ; B: [K][N] fp32 ; bias [N] fp32 ; res [M][N] ; C [M][N]
template<int LN, int AFF, int GEL, int RES, int AF32, int RF32, int OF32>
__global__ __launch_bounds__(256) void gemm_kernel(
    const void* __restrict__ Av, const float* __restrict__ stats,
    const float* __restrict__ gam, const float* __restrict__ bet,
    const float* __restrict__ B, const float* __restrict__ bias,
    const void* __restrict__ resv, void* __restrict__ Coutv,
    int M, int N, int K)
{
  __shared__ float As[16][132];
  __shared__ float Bs[16][132];
  const int t  = threadIdx.x;
  const int n0 = blockIdx.x * 128;
  const int m0 = blockIdx.y * 128;
  const int ty = t >> 4, tx = t & 15;
  const int ar = t >> 1, ac8 = (t & 1) * 8;
  const int br = t >> 4, bc8 = (t & 15) * 8;

  const float* Af = (const float*)Av;
  const u16*   Ab = (const u16*)Av;

  float mean = 0.f, rstd = 1.f;
  if (LN) {
    mean = stats[2*(m0+ar)];
    rstd = stats[2*(m0+ar)+1];
  }
  float acc[8][8];
  #pragma unroll
  for (int i = 0; i < 8; i++)
    #pragma unroll
    for (int j = 0; j < 8; j++) acc[i][j] = 0.f;

  const size_t arow = (size_t)(m0+ar)*K + ac8;
  const float* Bp = B + (size_t)br*N + n0 + bc8;

  for (int k0 = 0; k0 < K; k0 += 16) {
    float av[8], bv[8];
    if (AF32) {
      float4 a0 = *(const float4*)(Af + arow + k0);
      float4 a1 = *(const float4*)(Af + arow + k0 + 4);
      av[0]=a0.x; av[1]=a0.y; av[2]=a0.z; av[3]=a0.w;
      av[4]=a1.x; av[5]=a1.y; av[6]=a1.z; av[7]=a1.w;
    } else {
      uint4 araw = *(const uint4*)(Ab + arow + k0);
      decode8(araw, av);
    }
    {
      float4 b0 = *(const float4*)(Bp + (size_t)k0 * N);
      float4 b1 = *(const float4*)(Bp + (size_t)k0 * N + 4);
      bv[0]=b0.x; bv[1]=b0.y; bv[2]=b0.z; bv[3]=b0.w;
      bv[4]=b1.x; bv[5]=b1.y; bv[6]=b1.z; bv[7]=b1.w;
    }
    if (LN) {
      #pragma unroll
      for (int i = 0; i < 8; i++) av[i] = (av[i] - mean) * rstd;
      if (AFF) {
        float4 g0 = *(const float4*)(gam + k0 + ac8);
        float4 g1 = *(const float4*)(gam + k0 + ac8 + 4);
        float4 w0 = *(const float4*)(bet + k0 + ac8);
        float4 w1 = *(const float4*)(bet + k0 + ac8 + 4);
        float gv[8] = {g0.x,g0.y,g0.z,g0.w,g1.x,g1.y,g1.z,g1.w};
        float tv[8] = {w0.x,w0.y,w0.z,w0.w,w1.x,w1.y,w1.z,w1.w};
        #pragma unroll
        for (int i = 0; i < 8; i++) av[i] = av[i] * gv[i] + tv[i];
      }
    }
    #pragma unroll
    for (int i = 0; i < 8; i++) As[ac8+i][ar] = av[i];
    *(float4*)&Bs[br][bc8]   = make_float4(bv[0], bv[1], bv[2], bv[3]);
    *(float4*)&Bs[br][bc8+4] = make_float4(bv[4], bv[5], bv[6], bv[7]);
    __syncthreads();
    #pragma unroll
    for (int k = 0; k < 16; k++) {
      float4 a0 = *(const float4*)&As[k][ty*8];
      float4 a1 = *(const float4*)&As[k][ty*8+4];
      float4 b0 = *(const float4*)&Bs[k][tx*8];
      float4 b1 = *(const float4*)&Bs[k][tx*8+4];
      float aa[8] = {a0.x,a0.y,a0.z,a0.w,a1.x,a1.y,a1.z,a1.w};
      float bb[8] = {b0.x,b0.y,b0.z,b0.w,b1.x,b1.y,b1.z,b1.w};
      #pragma unroll
      for (int i = 0; i < 8; i++)
        #pragma unroll
        for (int j = 0; j < 8; j++)
          acc[i][j] = fmaf(aa[i], bb[j], acc[i][j]);
    }
    __syncthreads();
  }

  #pragma unroll
  for (int i = 0; i < 8; i++) {
    int m = m0 + ty*8 + i;
    float cv[8];
    #pragma unroll
    for (int j = 0; j < 8; j++) {
      int n = n0 + tx*8 + j;
      float c = acc[i][j] + bias[n];
      if (GEL) c = gelu_tanh(c);
      if (RES) {
        if (RF32) c += ((const float*)resv)[(size_t)m*N + n];
        else      c += bf2f(((const u16*)resv)[(size_t)m*N + n]);
      }
      cv[j] = c;
    }
    if (OF32) {
      float* Cf = (float*)Coutv;
      *(float4*)(Cf + (size_t)m*N + n0 + tx*8)     = make_float4(cv[0],cv[1],cv[2],cv[3]);
      *(float4*)(Cf + (size_t)m*N + n0 + tx*8 + 4) = make_float4(cv[4],cv[5],cv[6],cv[7]);
    } else {
      u16* Cb = (u16*)Coutv;
      u16 tmp[8];
      #pragma unroll
      for (int j = 0; j < 8; j++) tmp[j] = f2bf(cv[j]);
      uint4 pk = make_uint4((u32)tmp[0] | ((u32)tmp[1] << 16),
                            (u32)tmp[2] | ((u32)tmp[3] << 16),
                            (u32)tmp[4] | ((u32)tmp[5] << 16),
                            (u32)tmp[6] | ((u32)tmp[7] << 16));
      *(uint4*)(Cb + (size_t)m*N + n0 + tx*8) = pk;
    }
  }
}

// ---------------- attention: per (16 queries, head, batch) ----------------
// q: [BT][NQ][C] bf16 ; kv: chunk [cb][NC][2C] bf16 ; o: [BT][NQ][C] bf16
__global__ __launch_bounds__(256) void attn_kernel(
    const u16* __restrict__ q, const u16* __restrict__ kv,
    const u8* __restrict__ keep, u16* __restrict__ o, int b0)
{
  __shared__ float sc[16][NCn];      // 64 KB scores
  __shared__ float qs[16][DHn];      // 3 KB
  __shared__ float vt[256][52];      // 53.25 KB v tile
  __shared__ float red[16][17];
  __shared__ float rmax_s[16];
  __shared__ float rsum_s[16];

  const int t  = threadIdx.x;
  const int qg = blockIdx.x, h = blockIdx.y, bz = blockIdx.z;
  const int b  = b0 + bz;
  const int q0 = qg * 16;

  // load q tile (16 x 48) to LDS
  for (int i = t; i < 16*DHn; i += 256) {
    int qi = i / DHn, d = i % DHn;
    qs[qi][d] = bf2f(q[((size_t)b*NQn + q0 + qi)*Cd + h*DHn + d]);
  }
  __syncthreads();

  // scores: each thread owns key rows {t, t+256, t+512, t+768}
  for (int rep = 0; rep < 4; rep++) {
    const int kj = rep*256 + t;
    const u16* kp = kv + ((size_t)bz*NCn + kj)*(2*Cd) + h*DHn;
    float kr[48];
    #pragma unroll
    for (int i2 = 0; i2 < 12; i2++) {
      uint2 u = *(const uint2*)(kp + 4*i2);
      kr[4*i2+0] = bf2f(u.x & 0xffffu); kr[4*i2+1] = bf2f(u.x >> 16);
      kr[4*i2+2] = bf2f(u.y & 0xffffu); kr[4*i2+3] = bf2f(u.y >> 16);
    }
    #pragma unroll 4
    for (int qi = 0; qi < 16; qi++) {
      float s = 0.f;
      #pragma unroll
      for (int d = 0; d < 48; d += 4) {
        float4 qv = *(const float4*)&qs[qi][d];
        s = fmaf(qv.x, kr[d+0], s); s = fmaf(qv.y, kr[d+1], s);
        s = fmaf(qv.z, kr[d+2], s); s = fmaf(qv.w, kr[d+3], s);
      }
      sc[qi][kj] = s * ATT_SCALE;
    }
  }
  __syncthreads();

  // softmax per row; masked-out rows (keep==0) -> uniform 1/NC (bias=-MAX makes all equal)
  const int r = t >> 4, l = t & 15;
  const bool kp_ = keep[b*NQn + q0 + r] != 0;
  float lmax = -3.0e38f;
  for (int j = l; j < NCn; j += 16) lmax = fmaxf(lmax, sc[r][j]);
  red[r][l] = lmax;
  __syncthreads();
  if (l == 0) {
    float m = red[r][0];
    #pragma unroll
    for (int i = 1; i < 16; i++) m = fmaxf(m, red[r][i]);
    rmax_s[r] = m;
  }
  __syncthreads();
  float rm = rmax_s[r];
  float lsum = 0.f;
  for (int j = l; j < NCn; j += 16) {
    float e = __expf(sc[r][j] - rm);
    sc[r][j] = e;
    lsum += e;
  }
  red[r][l] = lsum;
  __syncthreads();
  if (l == 0) {
    float s = 0.f;
    #pragma unroll
    for (int i = 0; i < 16; i++) s += red[r][i];
    rsum_s[r] = s;
  }
  __syncthreads();
  if (kp_) {
    float inv = 1.f / rsum_s[r];
    for (int j = l; j < NCn; j += 16) sc[r][j] *= inv;
  } else {
    for (int j = l; j < NCn; j += 16) sc[r][j] = (1.f / NCn);
  }

  // PV: thread (t<192) owns (qi = t/12, d4 = (t%12)*4); v staged 256 rows at a time
  float acc0 = 0.f, acc1 = 0.f, acc2 = 0.f, acc3 = 0.f;
  const int oqi = t / 12, od4 = (t % 12) * 4;
  for (int kt = 0; kt < 4; kt++) {
    __syncthreads();
    {
      const u16* vp = kv + ((size_t)bz*NCn + kt*256 + t)*(2*Cd) + Cd + h*DHn;
      #pragma unroll
      for (int i2 = 0; i2 < 12; i2++) {
        uint2 u = *(const uint2*)(vp + 4*i2);
        float4 vv = make_float4(bf2f(u.x & 0xffffu), bf2f(u.x >> 16),
                                bf2f(u.y & 0xffffu), bf2f(u.y >> 16));
        *(float4*)&vt[t][4*i2] = vv;
      }
    }
    __syncthreads();
    if (t < 192) {
      #pragma unroll 2
      for (int j4 = 0; j4 < 256; j4 += 4) {
        float4 w  = *(const float4*)&sc[oqi][kt*256 + j4];
        float4 v0 = *(const float4*)&vt[j4+0][od4];
        float4 v1 = *(const float4*)&vt[j4+1][od4];
        float4 v2 = *(const float4*)&vt[j4+2][od4];
        float4 v3 = *(const float4*)&vt[j4+3][od4];
        acc0 += w.x*v0.x + w.y*v1.x + w.z*v2.x + w.w*v3.x;
        acc1 += w.x*v0.y + w.y*v1.y + w.z*v2.y + w.w*v3.y;
        acc2 += w.x*v0.z + w.y*v1.z + w.z*v2.z + w.w*v3.z;
        acc3 += w.x*v0.w + w.y*v1.w + w.z*v2.w + w.w*v3.w;
      }
    }
  }
  if (t < 192) {
    u16 p0 = f2bf(acc0), p1 = f2bf(acc1), p2 = f2bf(acc2), p3 = f2bf(acc3);
    uint2 pk = make_uint2((u32)p0 | ((u32)p1 << 16), (u32)p2 | ((u32)p3 << 16));
    *(uint2*)(o + ((size_t)b*NQn + q0 + oqi)*Cd + h*DHn + od4) = pk;
  }
}

// --------------------------------------------------------------------------
extern "C" void kernel_launch(void* const* d_in, const int* in_sizes, int n_in,
                              void* d_out, int out_size, void* d_ws, size_t ws_size,
                              hipStream_t stream) {
  (void)in_sizes; (void)n_in; (void)out_size;
  const float* x   = (const float*)d_in[0];
  const float* ctx = (const float*)d_in[1];
  const u8*    msk = (const u8*)   d_in[2];
  const float* Wq  = (const float*)d_in[3];
  const float* bq  = (const float*)d_in[4];
  const float* Wkv = (const float*)d_in[5];
  const float* bkv = (const float*)d_in[6];
  const float* Wo  = (const float*)d_in[7];
  const float* bo  = (const float*)d_in[8];
  const float* gc  = (const float*)d_in[9];
  const float* bc  = (const float*)d_in[10];
  const float* W1  = (const float*)d_in[11];
  const float* b1  = (const float*)d_in[12];
  const float* W2  = (const float*)d_in[13];
  const float* b2  = (const float*)d_in[14];
  float* out = (float*)d_out;

  char* ws = (char*)d_ws;
  size_t off = 0;
  auto bump = [&](size_t bytes) -> size_t {
    size_t o = off; off += (bytes + 255) & ~(size_t)255; return o;
  };
  size_t o_keep = bump(ROWSX);
  size_t o_xst  = bump((size_t)ROWSX * 2 * 4);
  size_t o_cst  = bump((size_t)ROWSC * 2 * 4);
  size_t o_x1st = bump((size_t)ROWSX * 2 * 4);
  size_t o_q    = bump((size_t)ROWSX * Cd * 2);
  size_t o_ob   = bump((size_t)ROWSX * Cd * 2);
  size_t o_x1   = bump((size_t)ROWSX * Cd * 2);
  size_t o_hid  = bump((size_t)ROWSX * HIDn * 2);
  size_t fixedB = off;
  size_t per_b  = (size_t)NCn * 2 * Cd * 2;   // bytes of kv per batch (bf16)
  int CB = 1;
  if (ws_size > fixedB) {
    size_t c = (ws_size - fixedB) / per_b;
    CB = (int)(c > (size_t)BTn ? (size_t)BTn : c);
    if (CB < 1) CB = 1;
  }
  size_t o_kv = off;

  u8*    keep = (u8*)(ws + o_keep);
  float* xst  = (float*)(ws + o_xst);
  float* cst  = (float*)(ws + o_cst);
  float* x1st = (float*)(ws + o_x1st);
  u16*   qb   = (u16*)(ws + o_q);
  u16*   ob   = (u16*)(ws + o_ob);
  u16*   x1b  = (u16*)(ws + o_x1);
  u16*   hidb = (u16*)(ws + o_hid);
  u16*   kvb  = (u16*)(ws + o_kv);

  decode_mask_kernel<<<1, 256, 0, stream>>>(msk, keep);
  row_stats_kernel<1><<<ROWSX/4, 256, 0, stream>>>(x,   xst, ROWSX, 1e-6f);
  row_stats_kernel<1><<<ROWSC/4, 256, 0, stream>>>(ctx, cst, ROWSC, 1e-5f);

  // q = LN(x) @ Wq + bq          (A fp32, out bf16)
  gemm_kernel<1,0,0,0,1,0,0><<<dim3(Cd/128, ROWSX/128), 256, 0, stream>>>(
      x, xst, nullptr, nullptr, Wq, bq, nullptr, qb, ROWSX, Cd, Cd);

  // kv chunks + attention
  for (int b0 = 0; b0 < BTn; b0 += CB) {
    int cb = (BTn - b0) < CB ? (BTn - b0) : CB;
    gemm_kernel<1,1,0,0,1,0,0><<<dim3((2*Cd)/128, cb*NCn/128), 256, 0, stream>>>(
        ctx + (size_t)b0*NCn*Cd, cst + (size_t)b0*NCn*2, gc, bc,
        Wkv, bkv, nullptr, kvb, cb*NCn, 2*Cd, Cd);
    attn_kernel<<<dim3(NQn/16, Hn, cb), 256, 0, stream>>>(qb, kvb, keep, ob, b0);
  }

  // x1 = x + o @ Wo + bo         (A bf16, res fp32, out bf16)
  gemm_kernel<0,0,0,1,0,1,0><<<dim3(Cd/128, ROWSX/128), 256, 0, stream>>>(
      ob, nullptr, nullptr, nullptr, Wo, bo, x, x1b, ROWSX, Cd, Cd);

  row_stats_kernel<0><<<ROWSX/4, 256, 0, stream>>>(x1b, x1st, ROWSX, 1e-6f);

  // hidden = gelu(LN(x1) @ W1 + b1)   (A bf16, out bf16)
  gemm_kernel<1,0,1,0,0,0,0><<<dim3(HIDn/128, ROWSX/128), 256, 0, stream>>>(
      x1b, x1st, nullptr, nullptr, W1, b1, nullptr, hidb, ROWSX, HIDn, Cd);

  // out = x1 + hidden @ W2 + b2      (A bf16, res bf16, out fp32)
  gemm_kernel<0,0,0,1,0,0,1><<<dim3(Cd/128, ROWSX/128), 256, 0, stream>>>(
      hidb, nullptr, nullptr, nullptr, W2, b2, x1b, out, ROWSX, Cd, HIDn);
}

// Round 3
// 769.409 us; speedup vs baseline: 4.8964x; 4.8964x over previous
//
#include <hip/hip_runtime.h>
#include <hip/hip_bf16.h>
#include <math.h>

typedef unsigned int  u32;
typedef unsigned short u16;
typedef unsigned char u8;

#define BTn   192
#define NQn   64
#define NCn   1024
#define Cd    384
#define Hn    8
#define DHn   48
#define HIDn  1536
#define ROWSX (BTn*NQn)     /* 12288 */
#define ROWSC (BTn*NCn)     /* 196608 */
#define ATT_SCALE 0.14433756729740643f

typedef __bf16 bf16x8 __attribute__((ext_vector_type(8)));
typedef float  f32x4  __attribute__((ext_vector_type(4)));

#define GLL16(gp, lp) __builtin_amdgcn_global_load_lds( \
    (const __attribute__((address_space(1))) void*)(gp), \
    (__attribute__((address_space(3))) void*)(lp), 16, 0, 0)

__device__ __forceinline__ float bf2f(u32 u) {
  union { u32 i; float f; } v; v.i = u << 16; return v.f;
}
__device__ __forceinline__ u16 f2bf(float f) {
  union { float f; u32 i; } v; v.f = f;
  u32 x = v.i;
  x += 0x7fffu + ((x >> 16) & 1u);
  return (u16)(x >> 16);
}
__device__ __forceinline__ void decode8(uint4 r, float* v) {
  v[0]=bf2f(r.x & 0xffffu); v[1]=bf2f(r.x >> 16);
  v[2]=bf2f(r.y & 0xffffu); v[3]=bf2f(r.y >> 16);
  v[4]=bf2f(r.z & 0xffffu); v[5]=bf2f(r.z >> 16);
  v[6]=bf2f(r.w & 0xffffu); v[7]=bf2f(r.w >> 16);
}
__device__ __forceinline__ float gelu_f(float x) {
  float x3 = x*x*x;
  float z = 0.7978845608028654f*x + 0.035677408136300125f*x3;
  float e = __expf(2.f*z);
  float th = 1.f - 2.f/(e+1.f);
  return 0.5f*x*(1.f+th);
}

// ---------------- mask decode (robust to u8 / i32 / bf16 / f32 storage) ---
__global__ void decode_mask_kernel(const u8* __restrict__ m, u8* __restrict__ keep) {
  __shared__ int flags[3];
  int t = threadIdx.x;
  if (t < 3) flags[t] = 0;
  __syncthreads();
  int nonbin = 0, oddset = 0, low01 = 0;
  for (int i = t; i < ROWSX; i += 256) {
    u32 b = m[i];
    if (b > 1u) nonbin = 1;
    if ((i & 3) && b) oddset = 1;
    if (((i & 3) < 2) && b) low01 = 1;
  }
  if (nonbin) flags[0] = 1;
  if (oddset) flags[1] = 1;
  if (low01)  flags[2] = 1;
  __syncthreads();
  int mode = flags[0] ? (flags[2] ? 2 : 3) : (flags[1] ? 1 : 0);
  for (int i = t; i < ROWSX; i += 256) {
    u8 k;
    if (mode == 2)      k = (m[2*i] | m[2*i+1]) ? 1 : 0;
    else if (mode == 3) k = (((const float*)m)[i] != 0.f) ? 1 : 0;
    else if (mode == 1) k = m[i] ? 1 : 0;
    else                k = (((const int*)m)[i] != 0) ? 1 : 0;
    keep[i] = k;
  }
}

// ---------------- fused LayerNorm -> bf16 (wave per row) ------------------
template<int AFF, int SRCF32>
__global__ __launch_bounds__(256) void lnorm_kernel(
    const void* __restrict__ srcv, const float* __restrict__ gw,
    const float* __restrict__ bw, u16* __restrict__ dst, float eps)
{
  const int row  = blockIdx.x * 4 + (threadIdx.x >> 6);
  const int lane = threadIdx.x & 63;
  float v[6];
  if (SRCF32) {
    const float2* p = (const float2*)((const float*)srcv + (size_t)row*Cd);
    #pragma unroll
    for (int i = 0; i < 3; i++) { float2 u = p[lane + 64*i]; v[2*i]=u.x; v[2*i+1]=u.y; }
  } else {
    const u32* p = (const u32*)((const u16*)srcv + (size_t)row*Cd);
    #pragma unroll
    for (int i = 0; i < 3; i++) { u32 u = p[lane + 64*i]; v[2*i]=bf2f(u&0xffffu); v[2*i+1]=bf2f(u>>16); }
  }
  float s  = v[0]+v[1]+v[2]+v[3]+v[4]+v[5];
  float s2 = v[0]*v[0]+v[1]*v[1]+v[2]*v[2]+v[3]*v[3]+v[4]*v[4]+v[5]*v[5];
  #pragma unroll
  for (int o = 32; o >= 1; o >>= 1) { s += __shfl_xor(s, o); s2 += __shfl_xor(s2, o); }
  float mean = s * (1.0f/Cd);
  float var  = s2 * (1.0f/Cd) - mean*mean;
  var = var > 0.f ? var : 0.f;
  float rstd = rsqrtf(var + eps);
  u32* d32 = (u32*)(dst + (size_t)row*Cd);
  #pragma unroll
  for (int i = 0; i < 3; i++) {
    float y0 = (v[2*i]   - mean) * rstd;
    float y1 = (v[2*i+1] - mean) * rstd;
    if (AFF) {
      float2 gg = *(const float2*)(gw + 2*(lane + 64*i));
      float2 bb = *(const float2*)(bw + 2*(lane + 64*i));
      y0 = y0*gg.x + bb.x;
      y1 = y1*gg.y + bb.y;
    }
    d32[lane + 64*i] = (u32)f2bf(y0) | ((u32)f2bf(y1) << 16);
  }
}

// ---------------- weight transpose+convert: W[K][N] f32 -> WT[N][K] bf16 --
__global__ __launch_bounds__(256) void wconv_kernel(
    const float* __restrict__ W, u16* __restrict__ WT, int K, int N, int total)
{
  int idx = blockIdx.x * 256 + threadIdx.x;
  if (idx >= total) return;
  int k = idx / N, n = idx % N;
  WT[(size_t)n*K + k] = f2bf(W[idx]);
}

// ---------------- MFMA GEMM: C = ep( A @ WT^T + bias [+res] ) -------------
// A [M][K] bf16 ; WT [N][K] bf16 ; M%128==0, N%128==0, K%32==0
template<int GEL, int RES, int RF32, int OF32>
__global__ __launch_bounds__(256) void mgemm_kernel(
    const u16* __restrict__ A, const u16* __restrict__ WT,
    const float* __restrict__ bias, const void* __restrict__ resv,
    void* __restrict__ Coutv, int M, int N, int K)
{
  __shared__ u16 As[128*32];
  __shared__ u16 Bs[128*32];
  const int t = threadIdx.x;
  const int w = t >> 6, l = t & 63, l15 = l & 15, g = l >> 4;
  const int n0 = blockIdx.x * 128, m0 = blockIdx.y * 128;
  const int wm = (w & 1) * 64, wn = (w >> 1) * 64;

  const int arow = t >> 2;
  const int acol = (t & 3) * 8;
  const u16* Ag = A  + (size_t)(m0 + arow) * K + acol;
  const u16* Wg = WT + (size_t)(n0 + arow) * K + acol;
  const size_t rowskip = (size_t)64 * K;

  f32x4 acc[4][4];
  #pragma unroll
  for (int i = 0; i < 4; i++)
    #pragma unroll
    for (int j = 0; j < 4; j++) acc[i][j] = (f32x4){0.f, 0.f, 0.f, 0.f};

  for (int k0 = 0; k0 < K; k0 += 32) {
    GLL16(Ag + k0,           &As[t*8]);
    GLL16(Ag + k0 + rowskip, &As[2048 + t*8]);
    GLL16(Wg + k0,           &Bs[t*8]);
    GLL16(Wg + k0 + rowskip, &Bs[2048 + t*8]);
    __syncthreads();
    bf16x8 af[4], bf[4];
    #pragma unroll
    for (int i = 0; i < 4; i++)
      af[i] = *(const bf16x8*)&As[(wm + i*16 + l15)*32 + g*8];
    #pragma unroll
    for (int j = 0; j < 4; j++)
      bf[j] = *(const bf16x8*)&Bs[(wn + j*16 + l15)*32 + g*8];
    #pragma unroll
    for (int i = 0; i < 4; i++)
      #pragma unroll
      for (int j = 0; j < 4; j++)
        acc[i][j] = __builtin_amdgcn_mfma_f32_16x16x32_bf16(bf[j], af[i], acc[i][j], 0, 0, 0);
    __syncthreads();
  }

  // swapped operands => acc[i][j] reg p: row m, col nb+p (4 consecutive cols)
  const float* resf = (const float*)resv;
  const u16*   resb = (const u16*)resv;
  float* Cf = (float*)Coutv;
  u16*   Cb = (u16*)Coutv;
  #pragma unroll
  for (int j = 0; j < 4; j++) {
    const int nb = n0 + wn + j*16 + g*4;
    const float4 bv = *(const float4*)&bias[nb];
    #pragma unroll
    for (int i = 0; i < 4; i++) {
      const int m = m0 + wm + i*16 + l15;
      float c0 = acc[i][j][0] + bv.x;
      float c1 = acc[i][j][1] + bv.y;
      float c2 = acc[i][j][2] + bv.z;
      float c3 = acc[i][j][3] + bv.w;
      if (GEL) { c0 = gelu_f(c0); c1 = gelu_f(c1); c2 = gelu_f(c2); c3 = gelu_f(c3); }
      if (RES) {
        if (RF32) {
          float4 r = *(const float4*)&resf[(size_t)m*N + nb];
          c0 += r.x; c1 += r.y; c2 += r.z; c3 += r.w;
        } else {
          uint2 r = *(const uint2*)&resb[(size_t)m*N + nb];
          c0 += bf2f(r.x & 0xffffu); c1 += bf2f(r.x >> 16);
          c2 += bf2f(r.y & 0xffffu); c3 += bf2f(r.y >> 16);
        }
      }
      if (OF32) {
        *(float4*)&Cf[(size_t)m*N + nb] = make_float4(c0, c1, c2, c3);
      } else {
        uint2 pk = make_uint2((u32)f2bf(c0) | ((u32)f2bf(c1) << 16),
                              (u32)f2bf(c2) | ((u32)f2bf(c3) << 16));
        *(uint2*)&Cb[(size_t)m*N + nb] = pk;
      }
    }
  }
}

// ---------------- flash attention, MFMA, one block per (b,h) --------------
// qb [ROWSX][C] bf16 (pre-scaled Q? no: scaled at staging); kv chunk [cb*NC][2C] bf16
__global__ __launch_bounds__(256) void fattn_kernel(
    const u16* __restrict__ qb, const u16* __restrict__ kvb,
    const u8* __restrict__ keep, u16* __restrict__ ob, int b0)
{
  __shared__ u16 Qs[64*72];       // [q][d pad 72], d 48..63 zero
  __shared__ u16 Ks[64*72];       // [kv][d pad 72], d 48..63 zero
  __shared__ u16 Vt[48*72];       // [d][kv pad 72]
  __shared__ u16 Ps[4][16*72];    // per-wave P [q16][kv pad 72]

  const int t = threadIdx.x;
  const int w = t >> 6, l = t & 63, l15 = l & 15, g = l >> 4;
  const int h = blockIdx.x, bz = blockIdx.y;
  const int b = b0 + bz;
  const int wq = w * 16;

  for (int i = t; i < 2304; i += 256) { ((u32*)Qs)[i] = 0; ((u32*)Ks)[i] = 0; }
  __syncthreads();

  // stage Q (scaled by ATT_SCALE)
  for (int i = t; i < 384; i += 256) {
    int row = i / 6, p = i % 6;
    uint4 v4 = *(const uint4*)(qb + (size_t)(b*NQn + row)*Cd + h*DHn + p*8);
    float f[8]; decode8(v4, f);
    u16 e[8];
    #pragma unroll
    for (int j = 0; j < 8; j++) e[j] = f2bf(f[j] * ATT_SCALE);
    uint4 pk = make_uint4((u32)e[0] | ((u32)e[1] << 16), (u32)e[2] | ((u32)e[3] << 16),
                          (u32)e[4] | ((u32)e[5] << 16), (u32)e[6] | ((u32)e[7] << 16));
    *(uint4*)&Qs[row*72 + p*8] = pk;
  }
  __syncthreads();

  bf16x8 qf0 = *(const bf16x8*)&Qs[(wq + l15)*72 + g*8];
  bf16x8 qf1 = *(const bf16x8*)&Qs[(wq + l15)*72 + 32 + g*8];

  u32 kw = *(const u32*)&keep[b*NQn + wq + g*4];
  float kf[4];
  #pragma unroll
  for (int r = 0; r < 4; r++) kf[r] = ((kw >> (8*r)) & 0xffu) ? 1.f : 0.f;

  float mrow[4], lrow[4];
  f32x4 oacc[3];
  #pragma unroll
  for (int r = 0; r < 4; r++) { mrow[r] = -3.0e38f; lrow[r] = 0.f; }
  #pragma unroll
  for (int d = 0; d < 3; d++) oacc[d] = (f32x4){0.f, 0.f, 0.f, 0.f};

  for (int kt = 0; kt < NCn/64; kt++) {
    __syncthreads();
    const size_t kbase = (size_t)bz*NCn + kt*64;
    for (int i = t; i < 384; i += 256) {
      int row = i / 6, p = i % 6;
      const u16* src = kvb + (kbase + row)*(2*Cd) + h*DHn + p*8;
      uint4 k4 = *(const uint4*)src;
      *(uint4*)&Ks[row*72 + p*8] = k4;
      uint4 v4 = *(const uint4*)(src + Cd);
      u16 ve[8] = {(u16)(v4.x&0xffffu),(u16)(v4.x>>16),(u16)(v4.y&0xffffu),(u16)(v4.y>>16),
                   (u16)(v4.z&0xffffu),(u16)(v4.z>>16),(u16)(v4.w&0xffffu),(u16)(v4.w>>16)};
      #pragma unroll
      for (int j = 0; j < 8; j++) Vt[(p*8+j)*72 + row] = ve[j];
    }
    __syncthreads();

    // S = Q K^T (pre-scaled)
    f32x4 sf[4];
    #pragma unroll
    for (int f = 0; f < 4; f++) {
      bf16x8 ka = *(const bf16x8*)&Ks[(f*16 + l15)*72 + g*8];
      bf16x8 kb = *(const bf16x8*)&Ks[(f*16 + l15)*72 + 32 + g*8];
      f32x4 z = (f32x4){0.f, 0.f, 0.f, 0.f};
      z = __builtin_amdgcn_mfma_f32_16x16x32_bf16(qf0, ka, z, 0, 0, 0);
      sf[f] = __builtin_amdgcn_mfma_f32_16x16x32_bf16(qf1, kb, z, 0, 0, 0);
    }

    // online softmax (q = wq + g*4 + r, kv cols spread over l15 + 16f)
    float p[4][4], sc_[4];
    #pragma unroll
    for (int r = 0; r < 4; r++) {
      float pmax = fmaxf(fmaxf(sf[0][r], sf[1][r]), fmaxf(sf[2][r], sf[3][r]));
      #pragma unroll
      for (int s = 1; s < 16; s <<= 1) pmax = fmaxf(pmax, __shfl_xor(pmax, s));
      float mn = kf[r] > 0.f ? fmaxf(mrow[r], pmax) : 0.f;
      sc_[r] = kf[r] > 0.f ? __expf(mrow[r] - mn) : 1.f;
      mrow[r] = mn;
      float p0 = kf[r] > 0.f ? __expf(sf[0][r] - mn) : 1.f;
      float p1 = kf[r] > 0.f ? __expf(sf[1][r] - mn) : 1.f;
      float p2 = kf[r] > 0.f ? __expf(sf[2][r] - mn) : 1.f;
      float p3 = kf[r] > 0.f ? __expf(sf[3][r] - mn) : 1.f;
      p[0][r]=p0; p[1][r]=p1; p[2][r]=p2; p[3][r]=p3;
      float ps = p0+p1+p2+p3;
      #pragma unroll
      for (int s = 1; s < 16; s <<= 1) ps += __shfl_xor(ps, s);
      lrow[r] = lrow[r]*sc_[r] + ps;
      oacc[0][r] *= sc_[r]; oacc[1][r] *= sc_[r]; oacc[2][r] *= sc_[r];
    }

    // P -> LDS (per-wave), bf16
    #pragma unroll
    for (int f = 0; f < 4; f++)
      #pragma unroll
      for (int r = 0; r < 4; r++)
        Ps[w][(g*4 + r)*72 + f*16 + l15] = f2bf(p[f][r]);

    // O += P V
    bf16x8 pa0 = *(const bf16x8*)&Ps[w][l15*72 + g*8];
    bf16x8 pa1 = *(const bf16x8*)&Ps[w][l15*72 + 32 + g*8];
    #pragma unroll
    for (int df = 0; df < 3; df++) {
      bf16x8 vb0 = *(const bf16x8*)&Vt[(df*16 + l15)*72 + g*8];
      bf16x8 vb1 = *(const bf16x8*)&Vt[(df*16 + l15)*72 + 32 + g*8];
      oacc[df] = __builtin_amdgcn_mfma_f32_16x16x32_bf16(pa0, vb0, oacc[df], 0, 0, 0);
      oacc[df] = __builtin_amdgcn_mfma_f32_16x16x32_bf16(pa1, vb1, oacc[df], 0, 0, 0);
    }
  }

  #pragma unroll
  for (int r = 0; r < 4; r++) {
    float inv = 1.f / lrow[r];
    size_t qrow = (size_t)(b*NQn + wq + g*4 + r);
    #pragma unroll
    for (int df = 0; df < 3; df++)
      ob[qrow*Cd + h*DHn + df*16 + l15] = f2bf(oacc[df][r] * inv);
  }
}

// --------------------------------------------------------------------------
extern "C" void kernel_launch(void* const* d_in, const int* in_sizes, int n_in,
                              void* d_out, int out_size, void* d_ws, size_t ws_size,
                              hipStream_t stream) {
  (void)in_sizes; (void)n_in; (void)out_size;
  const float* x   = (const float*)d_in[0];
  const float* ctx = (const float*)d_in[1];
  const u8*    msk = (const u8*)   d_in[2];
  const float* Wq  = (const float*)d_in[3];
  const float* bq  = (const float*)d_in[4];
  const float* Wkv = (const float*)d_in[5];
  const float* bkv = (const float*)d_in[6];
  const float* Wo  = (const float*)d_in[7];
  const float* bo  = (const float*)d_in[8];
  const float* gc  = (const float*)d_in[9];
  const float* bc  = (const float*)d_in[10];
  const float* W1  = (const float*)d_in[11];
  const float* b1  = (const float*)d_in[12];
  const float* W2  = (const float*)d_in[13];
  const float* b2  = (const float*)d_in[14];
  float* out = (float*)d_out;

  char* ws = (char*)d_ws;
  size_t off = 0;
  auto bump = [&](size_t bytes) -> size_t {
    size_t o = off; off += (bytes + 255) & ~(size_t)255; return o;
  };
  const size_t act = (size_t)ROWSX * Cd * 2;
  size_t o_keep = bump(ROWSX);
  size_t o_xn   = bump(act);
  size_t o_x1n  = bump(act);
  size_t o_q    = bump(act);
  size_t o_ob   = bump(act);
  size_t o_x1   = bump(act);
  size_t o_hid  = bump((size_t)4096 * HIDn * 2);
  size_t o_wtq  = bump((size_t)Cd*Cd*2);
  size_t o_wtkv = bump((size_t)Cd*2*Cd*2);
  size_t o_wto  = bump((size_t)Cd*Cd*2);
  size_t o_wt1  = bump((size_t)Cd*HIDn*2);
  size_t o_wt2  = bump((size_t)HIDn*Cd*2);
  size_t fixedB = off;
  const size_t cn_b = (size_t)NCn * Cd * 2;
  const size_t kv_b = (size_t)NCn * 2 * Cd * 2;
  int CB = 1;
  if (ws_size > fixedB) {
    size_t c = (ws_size - fixedB) / (cn_b + kv_b);
    CB = (int)(c > (size_t)BTn ? (size_t)BTn : c);
    if (CB < 1) CB = 1;
  }
  size_t o_cn = off;
  size_t o_kv = o_cn + (size_t)CB * cn_b;

  u8*  keep = (u8*)(ws + o_keep);
  u16* xn   = (u16*)(ws + o_xn);
  u16* x1n  = (u16*)(ws + o_x1n);
  u16* qb   = (u16*)(ws + o_q);
  u16* obuf = (u16*)(ws + o_ob);
  u16* x1b  = (u16*)(ws + o_x1);
  u16* hidb = (u16*)(ws + o_hid);
  u16* wtq  = (u16*)(ws + o_wtq);
  u16* wtkv = (u16*)(ws + o_wtkv);
  u16* wto  = (u16*)(ws + o_wto);
  u16* wt1  = (u16*)(ws + o_wt1);
  u16* wt2  = (u16*)(ws + o_wt2);
  u16* cnb  = (u16*)(ws + o_cn);
  u16* kvb  = (u16*)(ws + o_kv);

  decode_mask_kernel<<<1, 256, 0, stream>>>(msk, keep);

  wconv_kernel<<<(Cd*Cd+255)/256,     256, 0, stream>>>(Wq,  wtq,  Cd,   Cd,   Cd*Cd);
  wconv_kernel<<<(Cd*2*Cd+255)/256,   256, 0, stream>>>(Wkv, wtkv, Cd,   2*Cd, Cd*2*Cd);
  wconv_kernel<<<(Cd*Cd+255)/256,     256, 0, stream>>>(Wo,  wto,  Cd,   Cd,   Cd*Cd);
  wconv_kernel<<<(Cd*HIDn+255)/256,   256, 0, stream>>>(W1,  wt1,  Cd,   HIDn, Cd*HIDn);
  wconv_kernel<<<(HIDn*Cd+255)/256,   256, 0, stream>>>(W2,  wt2,  HIDn, Cd,   HIDn*Cd);

  lnorm_kernel<0,1><<<ROWSX/4, 256, 0, stream>>>(x, nullptr, nullptr, xn, 1e-6f);

  // q = LN(x) @ Wq + bq
  mgemm_kernel<0,0,0,0><<<dim3(Cd/128, ROWSX/128), 256, 0, stream>>>(
      xn, wtq, bq, nullptr, qb, ROWSX, Cd, Cd);

  for (int b0 = 0; b0 < BTn; b0 += CB) {
    int cb = (BTn - b0) < CB ? (BTn - b0) : CB;
    lnorm_kernel<1,1><<<cb*NCn/4, 256, 0, stream>>>(
        ctx + (size_t)b0*NCn*Cd, gc, bc, cnb, 1e-5f);
    mgemm_kernel<0,0,0,0><<<dim3(2*Cd/128, cb*NCn/128), 256, 0, stream>>>(
        cnb, wtkv, bkv, nullptr, kvb, cb*NCn, 2*Cd, Cd);
    fattn_kernel<<<dim3(Hn, cb), 256, 0, stream>>>(qb, kvb, keep, obuf, b0);
  }

  // x1 = x + o @ Wo + bo
  mgemm_kernel<0,1,1,0><<<dim3(Cd/128, ROWSX/128), 256, 0, stream>>>(
      obuf, wto, bo, x, x1b, ROWSX, Cd, Cd);

  lnorm_kernel<0,0><<<ROWSX/4, 256, 0, stream>>>(x1b, nullptr, nullptr, x1n, 1e-6f);

  // MLP in 3 row-chunks of 4096
  for (int rc = 0; rc < 3; rc++) {
    const size_t r0 = (size_t)rc * 4096;
    mgemm_kernel<1,0,0,0><<<dim3(HIDn/128, 4096/128), 256, 0, stream>>>(
        x1n + r0*Cd, wt1, b1, nullptr, hidb, 4096, HIDn, Cd);
    mgemm_kernel<0,1,0,1><<<dim3(Cd/128, 4096/128), 256, 0, stream>>>(
        hidb, wt2, b2, x1b + r0*Cd, out + r0*Cd, 4096, Cd, HIDn);
  }
}

// Round 4
// 739.769 us; speedup vs baseline: 5.0926x; 1.0401x over previous
//
#include <hip/hip_runtime.h>
#include <hip/hip_bf16.h>
#include <math.h>

typedef unsigned int  u32;
typedef unsigned short u16;
typedef unsigned char u8;

#define BTn   192
#define NQn   64
#define NCn   1024
#define Cd    384
#define Hn    8
#define DHn   48
#define HIDn  1536
#define ROWSX (BTn*NQn)     /* 12288 */
#define ROWSC (BTn*NCn)     /* 196608 */
#define ATT_SCALE 0.14433756729740643f
#define CBc   64            /* batch chunk: kvb+cnb = 151 MB, L3-resident */

typedef __bf16 bf16x8 __attribute__((ext_vector_type(8)));
typedef float  f32x4  __attribute__((ext_vector_type(4)));

#define GLL16(gp, lp) __builtin_amdgcn_global_load_lds( \
    (const __attribute__((address_space(1))) void*)(gp), \
    (__attribute__((address_space(3))) void*)(lp), 16, 0, 0)

__device__ __forceinline__ float bf2f(u32 u) {
  union { u32 i; float f; } v; v.i = u << 16; return v.f;
}
__device__ __forceinline__ u16 f2bf(float f) {
  union { float f; u32 i; } v; v.f = f;
  u32 x = v.i;
  x += 0x7fffu + ((x >> 16) & 1u);
  return (u16)(x >> 16);
}
__device__ __forceinline__ void decode8(uint4 r, float* v) {
  v[0]=bf2f(r.x & 0xffffu); v[1]=bf2f(r.x >> 16);
  v[2]=bf2f(r.y & 0xffffu); v[3]=bf2f(r.y >> 16);
  v[4]=bf2f(r.z & 0xffffu); v[5]=bf2f(r.z >> 16);
  v[6]=bf2f(r.w & 0xffffu); v[7]=bf2f(r.w >> 16);
}
__device__ __forceinline__ float gelu_f(float x) {
  float x3 = x*x*x;
  float z = 0.7978845608028654f*x + 0.035677408136300125f*x3;
  float e = __expf(2.f*z);
  float th = 1.f - 2.f/(e+1.f);
  return 0.5f*x*(1.f+th);
}

// ---------------- mask decode (robust to u8 / i32 / bf16 / f32 storage) ---
__global__ void decode_mask_kernel(const u8* __restrict__ m, u8* __restrict__ keep) {
  __shared__ int flags[3];
  int t = threadIdx.x;
  if (t < 3) flags[t] = 0;
  __syncthreads();
  int nonbin = 0, oddset = 0, low01 = 0;
  for (int i = t; i < ROWSX; i += 256) {
    u32 b = m[i];
    if (b > 1u) nonbin = 1;
    if ((i & 3) && b) oddset = 1;
    if (((i & 3) < 2) && b) low01 = 1;
  }
  if (nonbin) flags[0] = 1;
  if (oddset) flags[1] = 1;
  if (low01)  flags[2] = 1;
  __syncthreads();
  int mode = flags[0] ? (flags[2] ? 2 : 3) : (flags[1] ? 1 : 0);
  for (int i = t; i < ROWSX; i += 256) {
    u8 k;
    if (mode == 2)      k = (m[2*i] | m[2*i+1]) ? 1 : 0;
    else if (mode == 3) k = (((const float*)m)[i] != 0.f) ? 1 : 0;
    else if (mode == 1) k = m[i] ? 1 : 0;
    else                k = (((const int*)m)[i] != 0) ? 1 : 0;
    keep[i] = k;
  }
}

// ---------------- fused LayerNorm -> bf16 (wave per row) ------------------
template<int AFF, int SRCF32>
__global__ __launch_bounds__(256) void lnorm_kernel(
    const void* __restrict__ srcv, const float* __restrict__ gw,
    const float* __restrict__ bw, u16* __restrict__ dst, float eps)
{
  const int row  = blockIdx.x * 4 + (threadIdx.x >> 6);
  const int lane = threadIdx.x & 63;
  float v[6];
  if (SRCF32) {
    const float2* p = (const float2*)((const float*)srcv + (size_t)row*Cd);
    #pragma unroll
    for (int i = 0; i < 3; i++) { float2 u = p[lane + 64*i]; v[2*i]=u.x; v[2*i+1]=u.y; }
  } else {
    const u32* p = (const u32*)((const u16*)srcv + (size_t)row*Cd);
    #pragma unroll
    for (int i = 0; i < 3; i++) { u32 u = p[lane + 64*i]; v[2*i]=bf2f(u&0xffffu); v[2*i+1]=bf2f(u>>16); }
  }
  float s  = v[0]+v[1]+v[2]+v[3]+v[4]+v[5];
  float s2 = v[0]*v[0]+v[1]*v[1]+v[2]*v[2]+v[3]*v[3]+v[4]*v[4]+v[5]*v[5];
  #pragma unroll
  for (int o = 32; o >= 1; o >>= 1) { s += __shfl_xor(s, o); s2 += __shfl_xor(s2, o); }
  float mean = s * (1.0f/Cd);
  float var  = s2 * (1.0f/Cd) - mean*mean;
  var = var > 0.f ? var : 0.f;
  float rstd = rsqrtf(var + eps);
  u32* d32 = (u32*)(dst + (size_t)row*Cd);
  #pragma unroll
  for (int i = 0; i < 3; i++) {
    float y0 = (v[2*i]   - mean) * rstd;
    float y1 = (v[2*i+1] - mean) * rstd;
    if (AFF) {
      float2 gg = *(const float2*)(gw + 2*(lane + 64*i));
      float2 bb = *(const float2*)(bw + 2*(lane + 64*i));
      y0 = y0*gg.x + bb.x;
      y1 = y1*gg.y + bb.y;
    }
    d32[lane + 64*i] = (u32)f2bf(y0) | ((u32)f2bf(y1) << 16);
  }
}

// ---------------- weight transpose+convert: W[K][N] f32 -> WT[N][K] bf16 --
__global__ __launch_bounds__(256) void wconv_kernel(
    const float* __restrict__ W, u16* __restrict__ WT, int K, int N, int total)
{
  int idx = blockIdx.x * 256 + threadIdx.x;
  if (idx >= total) return;
  int k = idx / N, n = idx % N;
  WT[(size_t)n*K + k] = f2bf(W[idx]);
}

// ---------------- MFMA GEMM: C = ep( A @ WT^T + bias [+res] ) -------------
// A [M][K] bf16 ; WT [N][K] bf16 ; M%128==0, N%128==0, K%32==0
// 1D grid (nwg = nx*ny, % 8 == 0), XCD-contiguous remap.
// LDS XOR swizzle: 16B col-group g stored at slot g ^ ((row>>1)&3);
// global source pre-swizzled, GLL dest linear, ds_read applies same XOR.
template<int GEL, int RES, int RF32, int OF32>
__global__ __launch_bounds__(256) void mgemm_kernel(
    const u16* __restrict__ A, const u16* __restrict__ WT,
    const float* __restrict__ bias, const void* __restrict__ resv,
    void* __restrict__ Coutv, int M, int N, int K, int nx)
{
  __shared__ u16 As[128*32];
  __shared__ u16 Bs[128*32];
  const int t = threadIdx.x;
  const int w = t >> 6, l = t & 63, l15 = l & 15, g = l >> 4;

  // XCD-contiguous bijective remap (nwg % 8 == 0 for all our launches)
  const int nwg = gridDim.x;
  const int bid = blockIdx.x;
  const int wg  = (bid & 7) * (nwg >> 3) + (bid >> 3);
  const int n0 = (wg % nx) * 128, m0 = (wg / nx) * 128;
  const int wm = (w & 1) * 64, wn = (w >> 1) * 64;

  const int arow = t >> 2;                    // 0..63 (+64 on 2nd GLL)
  const int swk  = (t >> 3) & 3;              // (arow>>1)&3, same for arow+64
  const int acol = ((t & 3) ^ swk) * 8;       // pre-swizzled global col group
  const u16* Ag = A  + (size_t)(m0 + arow) * K + acol;
  const u16* Wg = WT + (size_t)(n0 + arow) * K + acol;
  const size_t rowskip = (size_t)64 * K;

  const int xk   = (l15 >> 1) & 3;            // read-side xor key
  const int goff = ((g ^ xk) << 3);           // swizzled 16B group offset (u16 units)

  f32x4 acc[4][4];
  #pragma unroll
  for (int i = 0; i < 4; i++)
    #pragma unroll
    for (int j = 0; j < 4; j++) acc[i][j] = (f32x4){0.f, 0.f, 0.f, 0.f};

  for (int k0 = 0; k0 < K; k0 += 32) {
    GLL16(Ag + k0,           &As[t*8]);
    GLL16(Ag + k0 + rowskip, &As[2048 + t*8]);
    GLL16(Wg + k0,           &Bs[t*8]);
    GLL16(Wg + k0 + rowskip, &Bs[2048 + t*8]);
    __syncthreads();
    bf16x8 af[4], bf[4];
    #pragma unroll
    for (int i = 0; i < 4; i++)
      af[i] = *(const bf16x8*)&As[(wm + i*16 + l15)*32 + goff];
    #pragma unroll
    for (int j = 0; j < 4; j++)
      bf[j] = *(const bf16x8*)&Bs[(wn + j*16 + l15)*32 + goff];
    #pragma unroll
    for (int i = 0; i < 4; i++)
      #pragma unroll
      for (int j = 0; j < 4; j++)
        acc[i][j] = __builtin_amdgcn_mfma_f32_16x16x32_bf16(bf[j], af[i], acc[i][j], 0, 0, 0);
    __syncthreads();
  }

  // swapped operands => acc[i][j] reg p: row m, col nb+p (4 consecutive cols)
  const float* resf = (const float*)resv;
  const u16*   resb = (const u16*)resv;
  float* Cf = (float*)Coutv;
  u16*   Cb = (u16*)Coutv;
  #pragma unroll
  for (int j = 0; j < 4; j++) {
    const int nb = n0 + wn + j*16 + g*4;
    const float4 bv = *(const float4*)&bias[nb];
    #pragma unroll
    for (int i = 0; i < 4; i++) {
      const int m = m0 + wm + i*16 + l15;
      float c0 = acc[i][j][0] + bv.x;
      float c1 = acc[i][j][1] + bv.y;
      float c2 = acc[i][j][2] + bv.z;
      float c3 = acc[i][j][3] + bv.w;
      if (GEL) { c0 = gelu_f(c0); c1 = gelu_f(c1); c2 = gelu_f(c2); c3 = gelu_f(c3); }
      if (RES) {
        if (RF32) {
          float4 r = *(const float4*)&resf[(size_t)m*N + nb];
          c0 += r.x; c1 += r.y; c2 += r.z; c3 += r.w;
        } else {
          uint2 r = *(const uint2*)&resb[(size_t)m*N + nb];
          c0 += bf2f(r.x & 0xffffu); c1 += bf2f(r.x >> 16);
          c2 += bf2f(r.y & 0xffffu); c3 += bf2f(r.y >> 16);
        }
      }
      if (OF32) {
        *(float4*)&Cf[(size_t)m*N + nb] = make_float4(c0, c1, c2, c3);
      } else {
        uint2 pk = make_uint2((u32)f2bf(c0) | ((u32)f2bf(c1) << 16),
                              (u32)f2bf(c2) | ((u32)f2bf(c3) << 16));
        *(uint2*)&Cb[(size_t)m*N + nb] = pk;
      }
    }
  }
}

// ---------------- flash attention, MFMA, one block per (b,h) --------------
__global__ __launch_bounds__(256) void fattn_kernel(
    const u16* __restrict__ qb, const u16* __restrict__ kvb,
    const u8* __restrict__ keep, u16* __restrict__ ob, int b0)
{
  __shared__ u16 Qs[64*72];       // [q][d pad 72], d 48..63 zero
  __shared__ u16 Ks[64*72];       // [kv][d pad 72], d 48..63 zero
  __shared__ u16 Vt[48*72];       // [d][kv pad 72]
  __shared__ u16 Ps[4][16*72];    // per-wave P [q16][kv pad 72]

  const int t = threadIdx.x;
  const int w = t >> 6, l = t & 63, l15 = l & 15, g = l >> 4;
  const int h = blockIdx.x, bz = blockIdx.y;
  const int b = b0 + bz;
  const int wq = w * 16;

  for (int i = t; i < 2304; i += 256) { ((u32*)Qs)[i] = 0; ((u32*)Ks)[i] = 0; }
  __syncthreads();

  // stage Q (scaled by ATT_SCALE)
  for (int i = t; i < 384; i += 256) {
    int row = i / 6, p = i % 6;
    uint4 v4 = *(const uint4*)(qb + (size_t)(b*NQn + row)*Cd + h*DHn + p*8);
    float f[8]; decode8(v4, f);
    u16 e[8];
    #pragma unroll
    for (int j = 0; j < 8; j++) e[j] = f2bf(f[j] * ATT_SCALE);
    uint4 pk = make_uint4((u32)e[0] | ((u32)e[1] << 16), (u32)e[2] | ((u32)e[3] << 16),
                          (u32)e[4] | ((u32)e[5] << 16), (u32)e[6] | ((u32)e[7] << 16));
    *(uint4*)&Qs[row*72 + p*8] = pk;
  }
  __syncthreads();

  bf16x8 qf0 = *(const bf16x8*)&Qs[(wq + l15)*72 + g*8];
  bf16x8 qf1 = *(const bf16x8*)&Qs[(wq + l15)*72 + 32 + g*8];

  u32 kw = *(const u32*)&keep[b*NQn + wq + g*4];
  float kf[4];
  #pragma unroll
  for (int r = 0; r < 4; r++) kf[r] = ((kw >> (8*r)) & 0xffu) ? 1.f : 0.f;

  float mrow[4], lrow[4];
  f32x4 oacc[3];
  #pragma unroll
  for (int r = 0; r < 4; r++) { mrow[r] = -3.0e38f; lrow[r] = 0.f; }
  #pragma unroll
  for (int d = 0; d < 3; d++) oacc[d] = (f32x4){0.f, 0.f, 0.f, 0.f};

  for (int kt = 0; kt < NCn/64; kt++) {
    __syncthreads();
    const size_t kbase = (size_t)bz*NCn + kt*64;
    for (int i = t; i < 384; i += 256) {
      int row = i / 6, p = i % 6;
      const u16* src = kvb + (kbase + row)*(2*Cd) + h*DHn + p*8;
      uint4 k4 = *(const uint4*)src;
      *(uint4*)&Ks[row*72 + p*8] = k4;
      uint4 v4 = *(const uint4*)(src + Cd);
      u16 ve[8] = {(u16)(v4.x&0xffffu),(u16)(v4.x>>16),(u16)(v4.y&0xffffu),(u16)(v4.y>>16),
                   (u16)(v4.z&0xffffu),(u16)(v4.z>>16),(u16)(v4.w&0xffffu),(u16)(v4.w>>16)};
      #pragma unroll
      for (int j = 0; j < 8; j++) Vt[(p*8+j)*72 + row] = ve[j];
    }
    __syncthreads();

    // S = Q K^T (pre-scaled)
    f32x4 sf[4];
    #pragma unroll
    for (int f = 0; f < 4; f++) {
      bf16x8 ka = *(const bf16x8*)&Ks[(f*16 + l15)*72 + g*8];
      bf16x8 kb = *(const bf16x8*)&Ks[(f*16 + l15)*72 + 32 + g*8];
      f32x4 z = (f32x4){0.f, 0.f, 0.f, 0.f};
      z = __builtin_amdgcn_mfma_f32_16x16x32_bf16(qf0, ka, z, 0, 0, 0);
      sf[f] = __builtin_amdgcn_mfma_f32_16x16x32_bf16(qf1, kb, z, 0, 0, 0);
    }

    // online softmax (q = wq + g*4 + r, kv cols spread over l15 + 16f)
    float p[4][4], sc_[4];
    #pragma unroll
    for (int r = 0; r < 4; r++) {
      float pmax = fmaxf(fmaxf(sf[0][r], sf[1][r]), fmaxf(sf[2][r], sf[3][r]));
      #pragma unroll
      for (int s = 1; s < 16; s <<= 1) pmax = fmaxf(pmax, __shfl_xor(pmax, s));
      float mn = kf[r] > 0.f ? fmaxf(mrow[r], pmax) : 0.f;
      sc_[r] = kf[r] > 0.f ? __expf(mrow[r] - mn) : 1.f;
      mrow[r] = mn;
      float p0 = kf[r] > 0.f ? __expf(sf[0][r] - mn) : 1.f;
      float p1 = kf[r] > 0.f ? __expf(sf[1][r] - mn) : 1.f;
      float p2 = kf[r] > 0.f ? __expf(sf[2][r] - mn) : 1.f;
      float p3 = kf[r] > 0.f ? __expf(sf[3][r] - mn) : 1.f;
      p[0][r]=p0; p[1][r]=p1; p[2][r]=p2; p[3][r]=p3;
      float ps = p0+p1+p2+p3;
      #pragma unroll
      for (int s = 1; s < 16; s <<= 1) ps += __shfl_xor(ps, s);
      lrow[r] = lrow[r]*sc_[r] + ps;
      oacc[0][r] *= sc_[r]; oacc[1][r] *= sc_[r]; oacc[2][r] *= sc_[r];
    }

    // P -> LDS (per-wave), bf16
    #pragma unroll
    for (int f = 0; f < 4; f++)
      #pragma unroll
      for (int r = 0; r < 4; r++)
        Ps[w][(g*4 + r)*72 + f*16 + l15] = f2bf(p[f][r]);

    // O += P V
    bf16x8 pa0 = *(const bf16x8*)&Ps[w][l15*72 + g*8];
    bf16x8 pa1 = *(const bf16x8*)&Ps[w][l15*72 + 32 + g*8];
    #pragma unroll
    for (int df = 0; df < 3; df++) {
      bf16x8 vb0 = *(const bf16x8*)&Vt[(df*16 + l15)*72 + g*8];
      bf16x8 vb1 = *(const bf16x8*)&Vt[(df*16 + l15)*72 + 32 + g*8];
      oacc[df] = __builtin_amdgcn_mfma_f32_16x16x32_bf16(pa0, vb0, oacc[df], 0, 0, 0);
      oacc[df] = __builtin_amdgcn_mfma_f32_16x16x32_bf16(pa1, vb1, oacc[df], 0, 0, 0);
    }
  }

  #pragma unroll
  for (int r = 0; r < 4; r++) {
    float inv = 1.f / lrow[r];
    size_t qrow = (size_t)(b*NQn + wq + g*4 + r);
    #pragma unroll
    for (int df = 0; df < 3; df++)
      ob[qrow*Cd + h*DHn + df*16 + l15] = f2bf(oacc[df][r] * inv);
  }
}

// --------------------------------------------------------------------------
extern "C" void kernel_launch(void* const* d_in, const int* in_sizes, int n_in,
                              void* d_out, int out_size, void* d_ws, size_t ws_size,
                              hipStream_t stream) {
  (void)in_sizes; (void)n_in; (void)out_size; (void)ws_size;
  const float* x   = (const float*)d_in[0];
  const float* ctx = (const float*)d_in[1];
  const u8*    msk = (const u8*)   d_in[2];
  const float* Wq  = (const float*)d_in[3];
  const float* bq  = (const float*)d_in[4];
  const float* Wkv = (const float*)d_in[5];
  const float* bkv = (const float*)d_in[6];
  const float* Wo  = (const float*)d_in[7];
  const float* bo  = (const float*)d_in[8];
  const float* gc  = (const float*)d_in[9];
  const float* bc  = (const float*)d_in[10];
  const float* W1  = (const float*)d_in[11];
  const float* b1  = (const float*)d_in[12];
  const float* W2  = (const float*)d_in[13];
  const float* b2  = (const float*)d_in[14];
  float* out = (float*)d_out;

  char* ws = (char*)d_ws;
  size_t off = 0;
  auto bump = [&](size_t bytes) -> size_t {
    size_t o = off; off += (bytes + 255) & ~(size_t)255; return o;
  };
  const size_t act = (size_t)ROWSX * Cd * 2;
  size_t o_keep = bump(ROWSX);
  size_t o_xn   = bump(act);
  size_t o_x1n  = bump(act);
  size_t o_q    = bump(act);
  size_t o_ob   = bump(act);
  size_t o_x1   = bump(act);
  size_t o_hid  = bump((size_t)4096 * HIDn * 2);
  size_t o_wtq  = bump((size_t)Cd*Cd*2);
  size_t o_wtkv = bump((size_t)Cd*2*Cd*2);
  size_t o_wto  = bump((size_t)Cd*Cd*2);
  size_t o_wt1  = bump((size_t)Cd*HIDn*2);
  size_t o_wt2  = bump((size_t)HIDn*Cd*2);
  size_t o_cn   = bump((size_t)CBc * NCn * Cd * 2);
  size_t o_kv   = bump((size_t)CBc * NCn * 2 * Cd * 2);

  u8*  keep = (u8*)(ws + o_keep);
  u16* xn   = (u16*)(ws + o_xn);
  u16* x1n  = (u16*)(ws + o_x1n);
  u16* qb   = (u16*)(ws + o_q);
  u16* obuf = (u16*)(ws + o_ob);
  u16* x1b  = (u16*)(ws + o_x1);
  u16* hidb = (u16*)(ws + o_hid);
  u16* wtq  = (u16*)(ws + o_wtq);
  u16* wtkv = (u16*)(ws + o_wtkv);
  u16* wto  = (u16*)(ws + o_wto);
  u16* wt1  = (u16*)(ws + o_wt1);
  u16* wt2  = (u16*)(ws + o_wt2);
  u16* cnb  = (u16*)(ws + o_cn);
  u16* kvb  = (u16*)(ws + o_kv);

  decode_mask_kernel<<<1, 256, 0, stream>>>(msk, keep);

  wconv_kernel<<<(Cd*Cd+255)/256,     256, 0, stream>>>(Wq,  wtq,  Cd,   Cd,   Cd*Cd);
  wconv_kernel<<<(Cd*2*Cd+255)/256,   256, 0, stream>>>(Wkv, wtkv, Cd,   2*Cd, Cd*2*Cd);
  wconv_kernel<<<(Cd*Cd+255)/256,     256, 0, stream>>>(Wo,  wto,  Cd,   Cd,   Cd*Cd);
  wconv_kernel<<<(Cd*HIDn+255)/256,   256, 0, stream>>>(W1,  wt1,  Cd,   HIDn, Cd*HIDn);
  wconv_kernel<<<(HIDn*Cd+255)/256,   256, 0, stream>>>(W2,  wt2,  HIDn, Cd,   HIDn*Cd);

  lnorm_kernel<0,1><<<ROWSX/4, 256, 0, stream>>>(x, nullptr, nullptr, xn, 1e-6f);

  // q = LN(x) @ Wq + bq
  mgemm_kernel<0,0,0,0><<<3*(ROWSX/128), 256, 0, stream>>>(
      xn, wtq, bq, nullptr, qb, ROWSX, Cd, Cd, 3);

  for (int b0 = 0; b0 < BTn; b0 += CBc) {
    lnorm_kernel<1,1><<<CBc*NCn/4, 256, 0, stream>>>(
        ctx + (size_t)b0*NCn*Cd, gc, bc, cnb, 1e-5f);
    mgemm_kernel<0,0,0,0><<<6*(CBc*NCn/128), 256, 0, stream>>>(
        cnb, wtkv, bkv, nullptr, kvb, CBc*NCn, 2*Cd, Cd, 6);
    fattn_kernel<<<dim3(Hn, CBc), 256, 0, stream>>>(qb, kvb, keep, obuf, b0);
  }

  // x1 = x + o @ Wo + bo
  mgemm_kernel<0,1,1,0><<<3*(ROWSX/128), 256, 0, stream>>>(
      obuf, wto, bo, x, x1b, ROWSX, Cd, Cd, 3);

  lnorm_kernel<0,0><<<ROWSX/4, 256, 0, stream>>>(x1b, nullptr, nullptr, x1n, 1e-6f);

  // MLP in 3 row-chunks of 4096
  for (int rc = 0; rc < 3; rc++) {
    const size_t r0 = (size_t)rc * 4096;
    mgemm_kernel<1,0,0,0><<<12*(4096/128), 256, 0, stream>>>(
        x1n + r0*Cd, wt1, b1, nullptr, hidb, 4096, HIDn, Cd, 12);
    mgemm_kernel<0,1,0,1><<<3*(4096/128), 256, 0, stream>>>(
        hidb, wt2, b2, x1b + r0*Cd, out + r0*Cd, 4096, Cd, HIDn, 3);
  }
}

// Round 5
// 715.468 us; speedup vs baseline: 5.2655x; 1.0340x over previous
//
#include <hip/hip_runtime.h>
#include <hip/hip_bf16.h>
#include <math.h>

typedef unsigned int  u32;
typedef unsigned short u16;
typedef unsigned char u8;

#define BTn   192
#define NQn   64
#define NCn   1024
#define Cd    384
#define Hn    8
#define DHn   48
#define HIDn  1536
#define ROWSX (BTn*NQn)     /* 12288 */
#define ROWSC (BTn*NCn)     /* 196608 */
#define ATT_SCALE 0.14433756729740643f
#define CBc   64            /* batch chunk: kvb+cnb = 151 MB, L3-resident */

typedef __bf16 bf16x8 __attribute__((ext_vector_type(8)));
typedef float  f32x4  __attribute__((ext_vector_type(4)));

#define GLL16(gp, lp) __builtin_amdgcn_global_load_lds( \
    (const __attribute__((address_space(1))) void*)(gp), \
    (__attribute__((address_space(3))) void*)(lp), 16, 0, 0)

__device__ __forceinline__ float bf2f(u32 u) {
  union { u32 i; float f; } v; v.i = u << 16; return v.f;
}
__device__ __forceinline__ u16 f2bf(float f) {
  union { float f; u32 i; } v; v.f = f;
  u32 x = v.i;
  x += 0x7fffu + ((x >> 16) & 1u);
  return (u16)(x >> 16);
}
__device__ __forceinline__ void decode8(uint4 r, float* v) {
  v[0]=bf2f(r.x & 0xffffu); v[1]=bf2f(r.x >> 16);
  v[2]=bf2f(r.y & 0xffffu); v[3]=bf2f(r.y >> 16);
  v[4]=bf2f(r.z & 0xffffu); v[5]=bf2f(r.z >> 16);
  v[6]=bf2f(r.w & 0xffffu); v[7]=bf2f(r.w >> 16);
}
__device__ __forceinline__ float gelu_f(float x) {
  float x3 = x*x*x;
  float z = 0.7978845608028654f*x + 0.035677408136300125f*x3;
  float e = __expf(2.f*z);
  float th = 1.f - 2.f/(e+1.f);
  return 0.5f*x*(1.f+th);
}

// ---------------- mask decode (robust to u8 / i32 / bf16 / f32 storage) ---
__global__ void decode_mask_kernel(const u8* __restrict__ m, u8* __restrict__ keep) {
  __shared__ int flags[3];
  int t = threadIdx.x;
  if (t < 3) flags[t] = 0;
  __syncthreads();
  int nonbin = 0, oddset = 0, low01 = 0;
  for (int i = t; i < ROWSX; i += 256) {
    u32 b = m[i];
    if (b > 1u) nonbin = 1;
    if ((i & 3) && b) oddset = 1;
    if (((i & 3) < 2) && b) low01 = 1;
  }
  if (nonbin) flags[0] = 1;
  if (oddset) flags[1] = 1;
  if (low01)  flags[2] = 1;
  __syncthreads();
  int mode = flags[0] ? (flags[2] ? 2 : 3) : (flags[1] ? 1 : 0);
  for (int i = t; i < ROWSX; i += 256) {
    u8 k;
    if (mode == 2)      k = (m[2*i] | m[2*i+1]) ? 1 : 0;
    else if (mode == 3) k = (((const float*)m)[i] != 0.f) ? 1 : 0;
    else if (mode == 1) k = m[i] ? 1 : 0;
    else                k = (((const int*)m)[i] != 0) ? 1 : 0;
    keep[i] = k;
  }
}

// ---------------- fused LayerNorm -> bf16 (wave per row) ------------------
template<int AFF, int SRCF32>
__global__ __launch_bounds__(256) void lnorm_kernel(
    const void* __restrict__ srcv, const float* __restrict__ gw,
    const float* __restrict__ bw, u16* __restrict__ dst, float eps)
{
  const int row  = blockIdx.x * 4 + (threadIdx.x >> 6);
  const int lane = threadIdx.x & 63;
  float v[6];
  if (SRCF32) {
    const float2* p = (const float2*)((const float*)srcv + (size_t)row*Cd);
    #pragma unroll
    for (int i = 0; i < 3; i++) { float2 u = p[lane + 64*i]; v[2*i]=u.x; v[2*i+1]=u.y; }
  } else {
    const u32* p = (const u32*)((const u16*)srcv + (size_t)row*Cd);
    #pragma unroll
    for (int i = 0; i < 3; i++) { u32 u = p[lane + 64*i]; v[2*i]=bf2f(u&0xffffu); v[2*i+1]=bf2f(u>>16); }
  }
  float s  = v[0]+v[1]+v[2]+v[3]+v[4]+v[5];
  float s2 = v[0]*v[0]+v[1]*v[1]+v[2]*v[2]+v[3]*v[3]+v[4]*v[4]+v[5]*v[5];
  #pragma unroll
  for (int o = 32; o >= 1; o >>= 1) { s += __shfl_xor(s, o); s2 += __shfl_xor(s2, o); }
  float mean = s * (1.0f/Cd);
  float var  = s2 * (1.0f/Cd) - mean*mean;
  var = var > 0.f ? var : 0.f;
  float rstd = rsqrtf(var + eps);
  u32* d32 = (u32*)(dst + (size_t)row*Cd);
  #pragma unroll
  for (int i = 0; i < 3; i++) {
    float y0 = (v[2*i]   - mean) * rstd;
    float y1 = (v[2*i+1] - mean) * rstd;
    if (AFF) {
      float2 gg = *(const float2*)(gw + 2*(lane + 64*i));
      float2 bb = *(const float2*)(bw + 2*(lane + 64*i));
      y0 = y0*gg.x + bb.x;
      y1 = y1*gg.y + bb.y;
    }
    d32[lane + 64*i] = (u32)f2bf(y0) | ((u32)f2bf(y1) << 16);
  }
}

// ------- tiled weight transpose+convert: W[K][N] f32 -> WT[N][K] bf16 -----
// grid = (K/64)*(N/64); coalesced read AND write via LDS bounce
__global__ __launch_bounds__(256) void wconvt_kernel(
    const float* __restrict__ W, u16* __restrict__ WT, int K, int N)
{
  __shared__ u16 tile[64][66];
  const int t  = threadIdx.x;
  const int nt = N >> 6;
  const int bk = blockIdx.x / nt, bn = blockIdx.x % nt;
  const int q  = t >> 6;          // 0..3
  const int nl = t & 63;
  #pragma unroll
  for (int r = 0; r < 16; r++) {
    int k = q*16 + r;
    tile[nl][k] = f2bf(W[(size_t)(bk*64 + k)*N + bn*64 + nl]);
  }
  __syncthreads();
  #pragma unroll
  for (int r = 0; r < 16; r++) {
    int n = q*16 + r;
    WT[(size_t)(bn*64 + n)*K + bk*64 + nl] = tile[n][nl];
  }
}

// ---------------- MFMA GEMM: C = ep( A @ WT^T + bias [+res] ) -------------
// A [M][K] bf16 ; WT [N][K] bf16 ; M%128==0, N%128==0, K%32==0
// 1D grid (nwg % 8 == 0), XCD-contiguous remap.
// LDS XOR swizzle both-sides; double-buffered 2-phase pipeline (T3-min).
template<int GEL, int RES, int RF32, int OF32>
__global__ __launch_bounds__(256) void mgemm_kernel(
    const u16* __restrict__ A, const u16* __restrict__ WT,
    const float* __restrict__ bias, const void* __restrict__ resv,
    void* __restrict__ Coutv, int M, int N, int K, int nx)
{
  __shared__ u16 As[2][4096];
  __shared__ u16 Bs[2][4096];
  const int t = threadIdx.x;
  const int w = t >> 6, l = t & 63, l15 = l & 15, g = l >> 4;

  const int nwg = gridDim.x;
  const int bid = blockIdx.x;
  const int wg  = (bid & 7) * (nwg >> 3) + (bid >> 3);
  const int n0 = (wg % nx) * 128, m0 = (wg / nx) * 128;
  const int wm = (w & 1) * 64, wn = (w >> 1) * 64;

  const int arow = t >> 2;                    // 0..63 (+64 on 2nd GLL)
  const int swk  = (t >> 3) & 3;              // (arow>>1)&3
  const int acol = ((t & 3) ^ swk) * 8;       // pre-swizzled global col group
  const u16* Ag = A  + (size_t)(m0 + arow) * K + acol;
  const u16* Wg = WT + (size_t)(n0 + arow) * K + acol;
  const size_t rowskip = (size_t)64 * K;

  const int xk   = (l15 >> 1) & 3;            // read-side xor key
  const int goff = ((g ^ xk) << 3);

  f32x4 acc[4][4];
  #pragma unroll
  for (int i = 0; i < 4; i++)
    #pragma unroll
    for (int j = 0; j < 4; j++) acc[i][j] = (f32x4){0.f, 0.f, 0.f, 0.f};

#define STAGE(nb, kk) do { \
    GLL16(Ag + (kk),           &As[nb][t*8]); \
    GLL16(Ag + (kk) + rowskip, &As[nb][2048 + t*8]); \
    GLL16(Wg + (kk),           &Bs[nb][t*8]); \
    GLL16(Wg + (kk) + rowskip, &Bs[nb][2048 + t*8]); \
  } while (0)

  STAGE(0, 0);
  asm volatile("s_waitcnt vmcnt(0)" ::: "memory");
  __builtin_amdgcn_s_barrier();
  __builtin_amdgcn_sched_barrier(0);

  const int nIter = K >> 5;
  #pragma unroll 2
  for (int it = 0; it < nIter; ++it) {
    const int cur = it & 1;
    if (it + 1 < nIter) STAGE(cur ^ 1, (it + 1) << 5);
    bf16x8 af[4], bfv[4];
    #pragma unroll
    for (int i = 0; i < 4; i++)
      af[i] = *(const bf16x8*)&As[cur][(wm + i*16 + l15)*32 + goff];
    #pragma unroll
    for (int j = 0; j < 4; j++)
      bfv[j] = *(const bf16x8*)&Bs[cur][(wn + j*16 + l15)*32 + goff];
    #pragma unroll
    for (int i = 0; i < 4; i++)
      #pragma unroll
      for (int j = 0; j < 4; j++)
        acc[i][j] = __builtin_amdgcn_mfma_f32_16x16x32_bf16(bfv[j], af[i], acc[i][j], 0, 0, 0);
    asm volatile("s_waitcnt vmcnt(0)" ::: "memory");
    __builtin_amdgcn_s_barrier();
    __builtin_amdgcn_sched_barrier(0);
  }
#undef STAGE

  // swapped operands => acc[i][j] reg p: row m, col nb+p (4 consecutive cols)
  const float* resf = (const float*)resv;
  const u16*   resb = (const u16*)resv;
  float* Cf = (float*)Coutv;
  u16*   Cb = (u16*)Coutv;
  #pragma unroll
  for (int j = 0; j < 4; j++) {
    const int nb = n0 + wn + j*16 + g*4;
    const float4 bv = *(const float4*)&bias[nb];
    #pragma unroll
    for (int i = 0; i < 4; i++) {
      const int m = m0 + wm + i*16 + l15;
      float c0 = acc[i][j][0] + bv.x;
      float c1 = acc[i][j][1] + bv.y;
      float c2 = acc[i][j][2] + bv.z;
      float c3 = acc[i][j][3] + bv.w;
      if (GEL) { c0 = gelu_f(c0); c1 = gelu_f(c1); c2 = gelu_f(c2); c3 = gelu_f(c3); }
      if (RES) {
        if (RF32) {
          float4 r = *(const float4*)&resf[(size_t)m*N + nb];
          c0 += r.x; c1 += r.y; c2 += r.z; c3 += r.w;
        } else {
          uint2 r = *(const uint2*)&resb[(size_t)m*N + nb];
          c0 += bf2f(r.x & 0xffffu); c1 += bf2f(r.x >> 16);
          c2 += bf2f(r.y & 0xffffu); c3 += bf2f(r.y >> 16);
        }
      }
      if (OF32) {
        *(float4*)&Cf[(size_t)m*N + nb] = make_float4(c0, c1, c2, c3);
      } else {
        uint2 pk = make_uint2((u32)f2bf(c0) | ((u32)f2bf(c1) << 16),
                              (u32)f2bf(c2) | ((u32)f2bf(c3) << 16));
        *(uint2*)&Cb[(size_t)m*N + nb] = pk;
      }
    }
  }
}

// ---------------- flash attention, MFMA, one block per (b,h) --------------
__global__ __launch_bounds__(256) void fattn_kernel(
    const u16* __restrict__ qb, const u16* __restrict__ kvb,
    const u8* __restrict__ keep, u16* __restrict__ ob, int b0)
{
  __shared__ u16 Qs[64*72];       // [q][d pad 72], d 48..63 zero
  __shared__ u16 Ks[64*72];       // [kv][d pad 72], d 48..63 zero
  __shared__ u16 Vt[48*72];       // [d][kv pad 72]
  __shared__ u16 Ps[4][16*72];    // per-wave P [q16][kv pad 72]

  const int t = threadIdx.x;
  const int w = t >> 6, l = t & 63, l15 = l & 15, g = l >> 4;
  const int h = blockIdx.x, bz = blockIdx.y;
  const int b = b0 + bz;
  const int wq = w * 16;

  for (int i = t; i < 2304; i += 256) { ((u32*)Qs)[i] = 0; ((u32*)Ks)[i] = 0; }
  __syncthreads();

  // stage Q (scaled by ATT_SCALE)
  for (int i = t; i < 384; i += 256) {
    int row = i / 6, p = i % 6;
    uint4 v4 = *(const uint4*)(qb + (size_t)(b*NQn + row)*Cd + h*DHn + p*8);
    float f[8]; decode8(v4, f);
    u16 e[8];
    #pragma unroll
    for (int j = 0; j < 8; j++) e[j] = f2bf(f[j] * ATT_SCALE);
    uint4 pk = make_uint4((u32)e[0] | ((u32)e[1] << 16), (u32)e[2] | ((u32)e[3] << 16),
                          (u32)e[4] | ((u32)e[5] << 16), (u32)e[6] | ((u32)e[7] << 16));
    *(uint4*)&Qs[row*72 + p*8] = pk;
  }
  __syncthreads();

  bf16x8 qf0 = *(const bf16x8*)&Qs[(wq + l15)*72 + g*8];
  bf16x8 qf1 = *(const bf16x8*)&Qs[(wq + l15)*72 + 32 + g*8];

  u32 kw = *(const u32*)&keep[b*NQn + wq + g*4];
  float kf[4];
  #pragma unroll
  for (int r = 0; r < 4; r++) kf[r] = ((kw >> (8*r)) & 0xffu) ? 1.f : 0.f;

  float mrow[4], lrow[4];
  f32x4 oacc[3];
  #pragma unroll
  for (int r = 0; r < 4; r++) { mrow[r] = -3.0e38f; lrow[r] = 0.f; }
  #pragma unroll
  for (int d = 0; d < 3; d++) oacc[d] = (f32x4){0.f, 0.f, 0.f, 0.f};

  for (int kt = 0; kt < NCn/64; kt++) {
    __syncthreads();
    const size_t kbase = (size_t)bz*NCn + kt*64;
    // K rows -> Ks (vector copies, 1.5 tasks/thread)
    for (int i = t; i < 384; i += 256) {
      int row = i / 6, p = i % 6;
      *(uint4*)&Ks[row*72 + p*8] =
          *(const uint4*)(kvb + (kbase + row)*(2*(size_t)Cd) + h*DHn + p*8);
    }
    // V 4x4 register transpose -> Vt (192 tasks)
    if (t < 192) {
      const int dq = (t >> 4) * 4;      // 0..44
      const int kq = (t & 15) * 4;      // 0..60
      const u16* vs = kvb + (kbase + kq)*(2*(size_t)Cd) + Cd + h*DHn + dq;
      u16 q0[4], q1[4], q2[4], q3[4];
      *(uint2*)q0 = *(const uint2*)(vs);
      *(uint2*)q1 = *(const uint2*)(vs + 2*Cd);
      *(uint2*)q2 = *(const uint2*)(vs + 4*Cd);
      *(uint2*)q3 = *(const uint2*)(vs + 6*Cd);
      #pragma unroll
      for (int j = 0; j < 4; j++) {
        u16 o4[4] = {q0[j], q1[j], q2[j], q3[j]};
        *(uint2*)&Vt[(dq+j)*72 + kq] = *(uint2*)o4;
      }
    }
    __syncthreads();

    // S = Q K^T (pre-scaled)
    f32x4 sf[4];
    #pragma unroll
    for (int f = 0; f < 4; f++) {
      bf16x8 ka = *(const bf16x8*)&Ks[(f*16 + l15)*72 + g*8];
      bf16x8 kb = *(const bf16x8*)&Ks[(f*16 + l15)*72 + 32 + g*8];
      f32x4 z = (f32x4){0.f, 0.f, 0.f, 0.f};
      z = __builtin_amdgcn_mfma_f32_16x16x32_bf16(qf0, ka, z, 0, 0, 0);
      sf[f] = __builtin_amdgcn_mfma_f32_16x16x32_bf16(qf1, kb, z, 0, 0, 0);
    }

    // online softmax (q = wq + g*4 + r, kv cols spread over l15 + 16f)
    float p[4][4], sc_[4];
    #pragma unroll
    for (int r = 0; r < 4; r++) {
      float pmax = fmaxf(fmaxf(sf[0][r], sf[1][r]), fmaxf(sf[2][r], sf[3][r]));
      #pragma unroll
      for (int s = 1; s < 16; s <<= 1) pmax = fmaxf(pmax, __shfl_xor(pmax, s));
      float mn = kf[r] > 0.f ? fmaxf(mrow[r], pmax) : 0.f;
      sc_[r] = kf[r] > 0.f ? __expf(mrow[r] - mn) : 1.f;
      mrow[r] = mn;
      float p0 = kf[r] > 0.f ? __expf(sf[0][r] - mn) : 1.f;
      float p1 = kf[r] > 0.f ? __expf(sf[1][r] - mn) : 1.f;
      float p2 = kf[r] > 0.f ? __expf(sf[2][r] - mn) : 1.f;
      float p3 = kf[r] > 0.f ? __expf(sf[3][r] - mn) : 1.f;
      p[0][r]=p0; p[1][r]=p1; p[2][r]=p2; p[3][r]=p3;
      float ps = p0+p1+p2+p3;
      #pragma unroll
      for (int s = 1; s < 16; s <<= 1) ps += __shfl_xor(ps, s);
      lrow[r] = lrow[r]*sc_[r] + ps;
      oacc[0][r] *= sc_[r]; oacc[1][r] *= sc_[r]; oacc[2][r] *= sc_[r];
    }

    // P -> LDS (per-wave), bf16
    #pragma unroll
    for (int f = 0; f < 4; f++)
      #pragma unroll
      for (int r = 0; r < 4; r++)
        Ps[w][(g*4 + r)*72 + f*16 + l15] = f2bf(p[f][r]);

    // O += P V
    bf16x8 pa0 = *(const bf16x8*)&Ps[w][l15*72 + g*8];
    bf16x8 pa1 = *(const bf16x8*)&Ps[w][l15*72 + 32 + g*8];
    #pragma unroll
    for (int df = 0; df < 3; df++) {
      bf16x8 vb0 = *(const bf16x8*)&Vt[(df*16 + l15)*72 + g*8];
      bf16x8 vb1 = *(const bf16x8*)&Vt[(df*16 + l15)*72 + 32 + g*8];
      oacc[df] = __builtin_amdgcn_mfma_f32_16x16x32_bf16(pa0, vb0, oacc[df], 0, 0, 0);
      oacc[df] = __builtin_amdgcn_mfma_f32_16x16x32_bf16(pa1, vb1, oacc[df], 0, 0, 0);
    }
  }

  #pragma unroll
  for (int r = 0; r < 4; r++) {
    float inv = 1.f / lrow[r];
    size_t qrow = (size_t)(b*NQn + wq + g*4 + r);
    #pragma unroll
    for (int df = 0; df < 3; df++)
      ob[qrow*Cd + h*DHn + df*16 + l15] = f2bf(oacc[df][r] * inv);
  }
}

// --------------------------------------------------------------------------
extern "C" void kernel_launch(void* const* d_in, const int* in_sizes, int n_in,
                              void* d_out, int out_size, void* d_ws, size_t ws_size,
                              hipStream_t stream) {
  (void)in_sizes; (void)n_in; (void)out_size; (void)ws_size;
  const float* x   = (const float*)d_in[0];
  const float* ctx = (const float*)d_in[1];
  const u8*    msk = (const u8*)   d_in[2];
  const float* Wq  = (const float*)d_in[3];
  const float* bq  = (const float*)d_in[4];
  const float* Wkv = (const float*)d_in[5];
  const float* bkv = (const float*)d_in[6];
  const float* Wo  = (const float*)d_in[7];
  const float* bo  = (const float*)d_in[8];
  const float* gc  = (const float*)d_in[9];
  const float* bc  = (const float*)d_in[10];
  const float* W1  = (const float*)d_in[11];
  const float* b1  = (const float*)d_in[12];
  const float* W2  = (const float*)d_in[13];
  const float* b2  = (const float*)d_in[14];
  float* out = (float*)d_out;

  char* ws = (char*)d_ws;
  size_t off = 0;
  auto bump = [&](size_t bytes) -> size_t {
    size_t o = off; off += (bytes + 255) & ~(size_t)255; return o;
  };
  const size_t act = (size_t)ROWSX * Cd * 2;
  size_t o_keep = bump(ROWSX);
  size_t o_xn   = bump(act);
  size_t o_x1n  = bump(act);
  size_t o_q    = bump(act);
  size_t o_ob   = bump(act);
  size_t o_x1   = bump(act);
  size_t o_hid  = bump((size_t)4096 * HIDn * 2);
  size_t o_wtq  = bump((size_t)Cd*Cd*2);
  size_t o_wtkv = bump((size_t)Cd*2*Cd*2);
  size_t o_wto  = bump((size_t)Cd*Cd*2);
  size_t o_wt1  = bump((size_t)Cd*HIDn*2);
  size_t o_wt2  = bump((size_t)HIDn*Cd*2);
  size_t o_cn   = bump((size_t)CBc * NCn * Cd * 2);
  size_t o_kv   = bump((size_t)CBc * NCn * 2 * Cd * 2);

  u8*  keep = (u8*)(ws + o_keep);
  u16* xn   = (u16*)(ws + o_xn);
  u16* x1n  = (u16*)(ws + o_x1n);
  u16* qb   = (u16*)(ws + o_q);
  u16* obuf = (u16*)(ws + o_ob);
  u16* x1b  = (u16*)(ws + o_x1);
  u16* hidb = (u16*)(ws + o_hid);
  u16* wtq  = (u16*)(ws + o_wtq);
  u16* wtkv = (u16*)(ws + o_wtkv);
  u16* wto  = (u16*)(ws + o_wto);
  u16* wt1  = (u16*)(ws + o_wt1);
  u16* wt2  = (u16*)(ws + o_wt2);
  u16* cnb  = (u16*)(ws + o_cn);
  u16* kvb  = (u16*)(ws + o_kv);

  decode_mask_kernel<<<1, 256, 0, stream>>>(msk, keep);

  wconvt_kernel<<<(Cd/64)*(Cd/64),     256, 0, stream>>>(Wq,  wtq,  Cd,   Cd);
  wconvt_kernel<<<(Cd/64)*(2*Cd/64),   256, 0, stream>>>(Wkv, wtkv, Cd,   2*Cd);
  wconvt_kernel<<<(Cd/64)*(Cd/64),     256, 0, stream>>>(Wo,  wto,  Cd,   Cd);
  wconvt_kernel<<<(Cd/64)*(HIDn/64),   256, 0, stream>>>(W1,  wt1,  Cd,   HIDn);
  wconvt_kernel<<<(HIDn/64)*(Cd/64),   256, 0, stream>>>(W2,  wt2,  HIDn, Cd);

  lnorm_kernel<0,1><<<ROWSX/4, 256, 0, stream>>>(x, nullptr, nullptr, xn, 1e-6f);

  // q = LN(x) @ Wq + bq
  mgemm_kernel<0,0,0,0><<<3*(ROWSX/128), 256, 0, stream>>>(
      xn, wtq, bq, nullptr, qb, ROWSX, Cd, Cd, 3);

  for (int b0 = 0; b0 < BTn; b0 += CBc) {
    lnorm_kernel<1,1><<<CBc*NCn/4, 256, 0, stream>>>(
        ctx + (size_t)b0*NCn*Cd, gc, bc, cnb, 1e-5f);
    mgemm_kernel<0,0,0,0><<<6*(CBc*NCn/128), 256, 0, stream>>>(
        cnb, wtkv, bkv, nullptr, kvb, CBc*NCn, 2*Cd, Cd, 6);
    fattn_kernel<<<dim3(Hn, CBc), 256, 0, stream>>>(qb, kvb, keep, obuf, b0);
  }

  // x1 = x + o @ Wo + bo
  mgemm_kernel<0,1,1,0><<<3*(ROWSX/128), 256, 0, stream>>>(
      obuf, wto, bo, x, x1b, ROWSX, Cd, Cd, 3);

  lnorm_kernel<0,0><<<ROWSX/4, 256, 0, stream>>>(x1b, nullptr, nullptr, x1n, 1e-6f);

  // MLP in 3 row-chunks of 4096
  for (int rc = 0; rc < 3; rc++) {
    const size_t r0 = (size_t)rc * 4096;
    mgemm_kernel<1,0,0,0><<<12*(4096/128), 256, 0, stream>>>(
        x1n + r0*Cd, wt1, b1, nullptr, hidb, 4096, HIDn, Cd, 12);
    mgemm_kernel<0,1,0,1><<<3*(4096/128), 256, 0, stream>>>(
        hidb, wt2, b2, x1b + r0*Cd, out + r0*Cd, 4096, Cd, HIDn, 3);
  }
}

// Round 6
// 667.516 us; speedup vs baseline: 5.6438x; 1.0718x over previous
//
#include <hip/hip_runtime.h>
#include <hip/hip_bf16.h>
#include <math.h>

typedef unsigned int  u32;
typedef unsigned short u16;
typedef unsigned char u8;

#define BTn   192
#define NQn   64
#define NCn   1024
#define Cd    384
#define Hn    8
#define DHn   48
#define HIDn  1536
#define ROWSX (BTn*NQn)     /* 12288 */
#define ROWSC (BTn*NCn)     /* 196608 */
#define ATT_SCALE 0.14433756729740643f
#define CBc   64            /* batch chunk: kvb+cnb = 151 MB, L3-resident */

typedef __bf16 bf16x8 __attribute__((ext_vector_type(8)));
typedef float  f32x4  __attribute__((ext_vector_type(4)));

#define GLL16(gp, lp) __builtin_amdgcn_global_load_lds( \
    (const __attribute__((address_space(1))) void*)(gp), \
    (__attribute__((address_space(3))) void*)(lp), 16, 0, 0)

__device__ __forceinline__ float bf2f(u32 u) {
  union { u32 i; float f; } v; v.i = u << 16; return v.f;
}
__device__ __forceinline__ u16 f2bf(float f) {
  union { float f; u32 i; } v; v.f = f;
  u32 x = v.i;
  x += 0x7fffu + ((x >> 16) & 1u);
  return (u16)(x >> 16);
}
__device__ __forceinline__ void decode8(uint4 r, float* v) {
  v[0]=bf2f(r.x & 0xffffu); v[1]=bf2f(r.x >> 16);
  v[2]=bf2f(r.y & 0xffffu); v[3]=bf2f(r.y >> 16);
  v[4]=bf2f(r.z & 0xffffu); v[5]=bf2f(r.z >> 16);
  v[6]=bf2f(r.w & 0xffffu); v[7]=bf2f(r.w >> 16);
}
__device__ __forceinline__ float gelu_f(float x) {
  float x3 = x*x*x;
  float z = 0.7978845608028654f*x + 0.035677408136300125f*x3;
  float e = __expf(2.f*z);
  float th = 1.f - 2.f/(e+1.f);
  return 0.5f*x*(1.f+th);
}

// ---------------- mask decode (robust to u8 / i32 / bf16 / f32 storage) ---
__global__ void decode_mask_kernel(const u8* __restrict__ m, u8* __restrict__ keep) {
  __shared__ int flags[3];
  int t = threadIdx.x;
  if (t < 3) flags[t] = 0;
  __syncthreads();
  int nonbin = 0, oddset = 0, low01 = 0;
  for (int i = t; i < ROWSX; i += 256) {
    u32 b = m[i];
    if (b > 1u) nonbin = 1;
    if ((i & 3) && b) oddset = 1;
    if (((i & 3) < 2) && b) low01 = 1;
  }
  if (nonbin) flags[0] = 1;
  if (oddset) flags[1] = 1;
  if (low01)  flags[2] = 1;
  __syncthreads();
  int mode = flags[0] ? (flags[2] ? 2 : 3) : (flags[1] ? 1 : 0);
  for (int i = t; i < ROWSX; i += 256) {
    u8 k;
    if (mode == 2)      k = (m[2*i] | m[2*i+1]) ? 1 : 0;
    else if (mode == 3) k = (((const float*)m)[i] != 0.f) ? 1 : 0;
    else if (mode == 1) k = m[i] ? 1 : 0;
    else                k = (((const int*)m)[i] != 0) ? 1 : 0;
    keep[i] = k;
  }
}

// ---------------- fused LayerNorm -> bf16 (wave per row) ------------------
template<int AFF, int SRCF32>
__global__ __launch_bounds__(256) void lnorm_kernel(
    const void* __restrict__ srcv, const float* __restrict__ gw,
    const float* __restrict__ bw, u16* __restrict__ dst, float eps)
{
  const int row  = blockIdx.x * 4 + (threadIdx.x >> 6);
  const int lane = threadIdx.x & 63;
  float v[6];
  if (SRCF32) {
    const float2* p = (const float2*)((const float*)srcv + (size_t)row*Cd);
    #pragma unroll
    for (int i = 0; i < 3; i++) { float2 u = p[lane + 64*i]; v[2*i]=u.x; v[2*i+1]=u.y; }
  } else {
    const u32* p = (const u32*)((const u16*)srcv + (size_t)row*Cd);
    #pragma unroll
    for (int i = 0; i < 3; i++) { u32 u = p[lane + 64*i]; v[2*i]=bf2f(u&0xffffu); v[2*i+1]=bf2f(u>>16); }
  }
  float s  = v[0]+v[1]+v[2]+v[3]+v[4]+v[5];
  float s2 = v[0]*v[0]+v[1]*v[1]+v[2]*v[2]+v[3]*v[3]+v[4]*v[4]+v[5]*v[5];
  #pragma unroll
  for (int o = 32; o >= 1; o >>= 1) { s += __shfl_xor(s, o); s2 += __shfl_xor(s2, o); }
  float mean = s * (1.0f/Cd);
  float var  = s2 * (1.0f/Cd) - mean*mean;
  var = var > 0.f ? var : 0.f;
  float rstd = rsqrtf(var + eps);
  u32* d32 = (u32*)(dst + (size_t)row*Cd);
  #pragma unroll
  for (int i = 0; i < 3; i++) {
    float y0 = (v[2*i]   - mean) * rstd;
    float y1 = (v[2*i+1] - mean) * rstd;
    if (AFF) {
      float2 gg = *(const float2*)(gw + 2*(lane + 64*i));
      float2 bb = *(const float2*)(bw + 2*(lane + 64*i));
      y0 = y0*gg.x + bb.x;
      y1 = y1*gg.y + bb.y;
    }
    d32[lane + 64*i] = (u32)f2bf(y0) | ((u32)f2bf(y1) << 16);
  }
}

// ------- tiled weight transpose+convert: W[K][N] f32 -> WT[N][K] bf16 -----
__global__ __launch_bounds__(256) void wconvt_kernel(
    const float* __restrict__ W, u16* __restrict__ WT, int K, int N)
{
  __shared__ u16 tile[64][66];
  const int t  = threadIdx.x;
  const int nt = N >> 6;
  const int bk = blockIdx.x / nt, bn = blockIdx.x % nt;
  const int q  = t >> 6;
  const int nl = t & 63;
  #pragma unroll
  for (int r = 0; r < 16; r++) {
    int k = q*16 + r;
    tile[nl][k] = f2bf(W[(size_t)(bk*64 + k)*N + bn*64 + nl]);
  }
  __syncthreads();
  #pragma unroll
  for (int r = 0; r < 16; r++) {
    int n = q*16 + r;
    WT[(size_t)(bn*64 + n)*K + bk*64 + nl] = tile[n][nl];
  }
}

// ---------------- MFMA GEMM: C = ep( A @ WT^T + bias [+res] ) -------------
// A [M][K] bf16 ; WT [N][K] bf16 ; M%128==0, N%128==0, K%96==0 (nIter%3==0)
// 3-buffer LDS, depth-2 prefetch, counted vmcnt (T3+T4), XOR swizzle (T2),
// XCD-contiguous remap (T1).
template<int GEL, int RES, int RF32, int OF32>
__global__ __launch_bounds__(256) void mgemm_kernel(
    const u16* __restrict__ A, const u16* __restrict__ WT,
    const float* __restrict__ bias, const void* __restrict__ resv,
    void* __restrict__ Coutv, int M, int N, int K, int nx)
{
  __shared__ u16 As[3][4096];
  __shared__ u16 Bs[3][4096];
  const int t = threadIdx.x;
  const int w = t >> 6, l = t & 63, l15 = l & 15, g = l >> 4;

  const int nwg = gridDim.x;
  const int bid = blockIdx.x;
  const int wg  = (bid & 7) * (nwg >> 3) + (bid >> 3);
  const int n0 = (wg % nx) * 128, m0 = (wg / nx) * 128;
  const int wm = (w & 1) * 64, wn = (w >> 1) * 64;

  const int arow = t >> 2;
  const int swk  = (t >> 3) & 3;
  const int acol = ((t & 3) ^ swk) * 8;       // pre-swizzled global col group
  const u16* Ag = A  + (size_t)(m0 + arow) * K + acol;
  const u16* Wg = WT + (size_t)(n0 + arow) * K + acol;
  const size_t rowskip = (size_t)64 * K;

  const int xk   = (l15 >> 1) & 3;
  const int goff = ((g ^ xk) << 3);

  f32x4 acc[4][4];
  #pragma unroll
  for (int i = 0; i < 4; i++)
    #pragma unroll
    for (int j = 0; j < 4; j++) acc[i][j] = (f32x4){0.f, 0.f, 0.f, 0.f};

  const int nIter = K >> 5;

#define STAGE(nb, kk) do { \
    GLL16(Ag + (kk),           &As[nb][t*8]); \
    GLL16(Ag + (kk) + rowskip, &As[nb][2048 + t*8]); \
    GLL16(Wg + (kk),           &Bs[nb][t*8]); \
    GLL16(Wg + (kk) + rowskip, &Bs[nb][2048 + t*8]); \
  } while (0)

#define BODY(BUF, IT) do { \
    const int it_ = (IT); \
    if (it_ + 2 < nIter) { \
      STAGE((BUF + 2) % 3, (it_ + 2) << 5); \
      asm volatile("s_waitcnt vmcnt(8)" ::: "memory"); \
    } else if (it_ + 1 < nIter) { \
      asm volatile("s_waitcnt vmcnt(4)" ::: "memory"); \
    } else { \
      asm volatile("s_waitcnt vmcnt(0)" ::: "memory"); \
    } \
    __builtin_amdgcn_s_barrier(); \
    __builtin_amdgcn_sched_barrier(0); \
    { \
      bf16x8 af[4], bfv[4]; \
      _Pragma("unroll") \
      for (int i = 0; i < 4; i++) \
        af[i] = *(const bf16x8*)&As[BUF][(wm + i*16 + l15)*32 + goff]; \
      _Pragma("unroll") \
      for (int j = 0; j < 4; j++) \
        bfv[j] = *(const bf16x8*)&Bs[BUF][(wn + j*16 + l15)*32 + goff]; \
      _Pragma("unroll") \
      for (int i = 0; i < 4; i++) \
        _Pragma("unroll") \
        for (int j = 0; j < 4; j++) \
          acc[i][j] = __builtin_amdgcn_mfma_f32_16x16x32_bf16(bfv[j], af[i], acc[i][j], 0, 0, 0); \
    } \
    __builtin_amdgcn_sched_barrier(0); \
    __builtin_amdgcn_s_barrier(); \
  } while (0)

  STAGE(0, 0);
  STAGE(1, 32);
  for (int it0 = 0; it0 < nIter; it0 += 3) {
    BODY(0, it0);
    BODY(1, it0 + 1);
    BODY(2, it0 + 2);
  }
#undef BODY
#undef STAGE

  const float* resf = (const float*)resv;
  const u16*   resb = (const u16*)resv;
  float* Cf = (float*)Coutv;
  u16*   Cb = (u16*)Coutv;
  #pragma unroll
  for (int j = 0; j < 4; j++) {
    const int nb = n0 + wn + j*16 + g*4;
    const float4 bv = *(const float4*)&bias[nb];
    #pragma unroll
    for (int i = 0; i < 4; i++) {
      const int m = m0 + wm + i*16 + l15;
      float c0 = acc[i][j][0] + bv.x;
      float c1 = acc[i][j][1] + bv.y;
      float c2 = acc[i][j][2] + bv.z;
      float c3 = acc[i][j][3] + bv.w;
      if (GEL) { c0 = gelu_f(c0); c1 = gelu_f(c1); c2 = gelu_f(c2); c3 = gelu_f(c3); }
      if (RES) {
        if (RF32) {
          float4 r = *(const float4*)&resf[(size_t)m*N + nb];
          c0 += r.x; c1 += r.y; c2 += r.z; c3 += r.w;
        } else {
          uint2 r = *(const uint2*)&resb[(size_t)m*N + nb];
          c0 += bf2f(r.x & 0xffffu); c1 += bf2f(r.x >> 16);
          c2 += bf2f(r.y & 0xffffu); c3 += bf2f(r.y >> 16);
        }
      }
      if (OF32) {
        *(float4*)&Cf[(size_t)m*N + nb] = make_float4(c0, c1, c2, c3);
      } else {
        uint2 pk = make_uint2((u32)f2bf(c0) | ((u32)f2bf(c1) << 16),
                              (u32)f2bf(c2) | ((u32)f2bf(c3) << 16));
        *(uint2*)&Cb[(size_t)m*N + nb] = pk;
      }
    }
  }
}

// ---------------- flash attention, MFMA, one block per (b,h) --------------
// T14 async-stage: next K/V tile loaded to regs at start of compute, written
// to LDS after the barrier; raw s_barrier (no vmcnt drain).
__global__ __launch_bounds__(256) void fattn_kernel(
    const u16* __restrict__ qb, const u16* __restrict__ kvb,
    const u8* __restrict__ keep, u16* __restrict__ ob, int b0)
{
  __shared__ u16 Qs[64*72];
  __shared__ u16 Ks[64*72];
  __shared__ u16 Vt[48*72];
  __shared__ u16 Ps[4][16*72];

  const int t = threadIdx.x;
  const int w = t >> 6, l = t & 63, l15 = l & 15, g = l >> 4;
  const int h = blockIdx.x, bz = blockIdx.y;
  const int b = b0 + bz;
  const int wq = w * 16;
  const int krow0 = t / 6, kp0 = t % 6;
  const int krow1 = (256 + t) / 6, kp1 = (256 + t) % 6;   // t<128
  const int vdq = (t >> 4) * 4, vkq = (t & 15) * 4;       // t<192

  for (int i = t; i < 2304; i += 256) { ((u32*)Qs)[i] = 0; ((u32*)Ks)[i] = 0; }
  __syncthreads();

  // stage Q (scaled by ATT_SCALE)
  for (int i = t; i < 384; i += 256) {
    int row = i / 6, p = i % 6;
    uint4 v4 = *(const uint4*)(qb + (size_t)(b*NQn + row)*Cd + h*DHn + p*8);
    float f[8]; decode8(v4, f);
    u16 e[8];
    #pragma unroll
    for (int j = 0; j < 8; j++) e[j] = f2bf(f[j] * ATT_SCALE);
    uint4 pk = make_uint4((u32)e[0] | ((u32)e[1] << 16), (u32)e[2] | ((u32)e[3] << 16),
                          (u32)e[4] | ((u32)e[5] << 16), (u32)e[6] | ((u32)e[7] << 16));
    *(uint4*)&Qs[row*72 + p*8] = pk;
  }

  u32 kw = *(const u32*)&keep[b*NQn + wq + g*4];
  float kf[4];
  #pragma unroll
  for (int r = 0; r < 4; r++) kf[r] = ((kw >> (8*r)) & 0xffu) ? 1.f : 0.f;

  float mrow[4], lrow[4];
  f32x4 oacc[3];
  #pragma unroll
  for (int r = 0; r < 4; r++) { mrow[r] = -3.0e38f; lrow[r] = 0.f; }
  #pragma unroll
  for (int d = 0; d < 3; d++) oacc[d] = (f32x4){0.f, 0.f, 0.f, 0.f};

  auto loadKV = [&](int kt, uint4& KR0, uint4& KR1, uint2* V) {
    const u16* base = kvb + ((size_t)bz*NCn + (size_t)kt*64) * (2*(size_t)Cd);
    KR0 = *(const uint4*)(base + (size_t)krow0*(2*Cd) + h*DHn + kp0*8);
    if (t < 128)
      KR1 = *(const uint4*)(base + (size_t)krow1*(2*Cd) + h*DHn + kp1*8);
    if (t < 192) {
      const u16* vs = base + (size_t)vkq*(2*Cd) + Cd + h*DHn + vdq;
      V[0] = *(const uint2*)(vs);
      V[1] = *(const uint2*)(vs + 2*Cd);
      V[2] = *(const uint2*)(vs + 4*Cd);
      V[3] = *(const uint2*)(vs + 6*Cd);
    }
  };
  auto writeKV = [&](const uint4& KR0, const uint4& KR1, const uint2* V) {
    *(uint4*)&Ks[krow0*72 + kp0*8] = KR0;
    if (t < 128) *(uint4*)&Ks[krow1*72 + kp1*8] = KR1;
    if (t < 192) {
      #pragma unroll
      for (int jj = 0; jj < 4; jj++) {
        u16 o4[4] = {((const u16*)&V[0])[jj], ((const u16*)&V[1])[jj],
                     ((const u16*)&V[2])[jj], ((const u16*)&V[3])[jj]};
        *(uint2*)&Vt[(vdq+jj)*72 + vkq] = *(uint2*)o4;
      }
    }
  };

  bf16x8 qf0, qf1;
  auto compute = [&]() {
    f32x4 sf[4];
    #pragma unroll
    for (int f = 0; f < 4; f++) {
      bf16x8 ka = *(const bf16x8*)&Ks[(f*16 + l15)*72 + g*8];
      bf16x8 kb = *(const bf16x8*)&Ks[(f*16 + l15)*72 + 32 + g*8];
      f32x4 z = (f32x4){0.f, 0.f, 0.f, 0.f};
      z = __builtin_amdgcn_mfma_f32_16x16x32_bf16(qf0, ka, z, 0, 0, 0);
      sf[f] = __builtin_amdgcn_mfma_f32_16x16x32_bf16(qf1, kb, z, 0, 0, 0);
    }
    float p[4][4], sc_[4];
    #pragma unroll
    for (int r = 0; r < 4; r++) {
      float pmax = fmaxf(fmaxf(sf[0][r], sf[1][r]), fmaxf(sf[2][r], sf[3][r]));
      #pragma unroll
      for (int s = 1; s < 16; s <<= 1) pmax = fmaxf(pmax, __shfl_xor(pmax, s));
      float mn = kf[r] > 0.f ? fmaxf(mrow[r], pmax) : 0.f;
      sc_[r] = kf[r] > 0.f ? __expf(mrow[r] - mn) : 1.f;
      mrow[r] = mn;
      float p0 = kf[r] > 0.f ? __expf(sf[0][r] - mn) : 1.f;
      float p1 = kf[r] > 0.f ? __expf(sf[1][r] - mn) : 1.f;
      float p2 = kf[r] > 0.f ? __expf(sf[2][r] - mn) : 1.f;
      float p3 = kf[r] > 0.f ? __expf(sf[3][r] - mn) : 1.f;
      p[0][r]=p0; p[1][r]=p1; p[2][r]=p2; p[3][r]=p3;
      float ps = p0+p1+p2+p3;
      #pragma unroll
      for (int s = 1; s < 16; s <<= 1) ps += __shfl_xor(ps, s);
      lrow[r] = lrow[r]*sc_[r] + ps;
      oacc[0][r] *= sc_[r]; oacc[1][r] *= sc_[r]; oacc[2][r] *= sc_[r];
    }
    #pragma unroll
    for (int f = 0; f < 4; f++)
      #pragma unroll
      for (int r = 0; r < 4; r++)
        Ps[w][(g*4 + r)*72 + f*16 + l15] = f2bf(p[f][r]);
    bf16x8 pa0 = *(const bf16x8*)&Ps[w][l15*72 + g*8];
    bf16x8 pa1 = *(const bf16x8*)&Ps[w][l15*72 + 32 + g*8];
    #pragma unroll
    for (int df = 0; df < 3; df++) {
      bf16x8 vb0 = *(const bf16x8*)&Vt[(df*16 + l15)*72 + g*8];
      bf16x8 vb1 = *(const bf16x8*)&Vt[(df*16 + l15)*72 + 32 + g*8];
      oacc[df] = __builtin_amdgcn_mfma_f32_16x16x32_bf16(pa0, vb0, oacc[df], 0, 0, 0);
      oacc[df] = __builtin_amdgcn_mfma_f32_16x16x32_bf16(pa1, vb1, oacc[df], 0, 0, 0);
    }
  };

  uint4 ka0, ka1, kb0_, kb1_;
  uint2 va[4], vb_[4];
  loadKV(0, ka0, ka1, va);
  __syncthreads();           // Q staged (drains everything incl. kt0 loads)

  qf0 = *(const bf16x8*)&Qs[(wq + l15)*72 + g*8];
  qf1 = *(const bf16x8*)&Qs[(wq + l15)*72 + 32 + g*8];

  for (int kt = 0; kt < 16; kt += 2) {
    // even tile
    writeKV(ka0, ka1, va);
    asm volatile("s_waitcnt lgkmcnt(0)" ::: "memory");
    __builtin_amdgcn_sched_barrier(0);
    __builtin_amdgcn_s_barrier();
    __builtin_amdgcn_sched_barrier(0);
    loadKV(kt + 1, kb0_, kb1_, vb_);
    compute();
    __builtin_amdgcn_sched_barrier(0);
    __builtin_amdgcn_s_barrier();
    // odd tile
    writeKV(kb0_, kb1_, vb_);
    asm volatile("s_waitcnt lgkmcnt(0)" ::: "memory");
    __builtin_amdgcn_sched_barrier(0);
    __builtin_amdgcn_s_barrier();
    __builtin_amdgcn_sched_barrier(0);
    if (kt + 2 < 16) loadKV(kt + 2, ka0, ka1, va);
    compute();
    if (kt + 2 < 16) {
      __builtin_amdgcn_sched_barrier(0);
      __builtin_amdgcn_s_barrier();
    }
  }

  #pragma unroll
  for (int r = 0; r < 4; r++) {
    float inv = 1.f / lrow[r];
    size_t qrow = (size_t)(b*NQn + wq + g*4 + r);
    #pragma unroll
    for (int df = 0; df < 3; df++)
      ob[qrow*Cd + h*DHn + df*16 + l15] = f2bf(oacc[df][r] * inv);
  }
}

// --------------------------------------------------------------------------
extern "C" void kernel_launch(void* const* d_in, const int* in_sizes, int n_in,
                              void* d_out, int out_size, void* d_ws, size_t ws_size,
                              hipStream_t stream) {
  (void)in_sizes; (void)n_in; (void)out_size; (void)ws_size;
  const float* x   = (const float*)d_in[0];
  const float* ctx = (const float*)d_in[1];
  const u8*    msk = (const u8*)   d_in[2];
  const float* Wq  = (const float*)d_in[3];
  const float* bq  = (const float*)d_in[4];
  const float* Wkv = (const float*)d_in[5];
  const float* bkv = (const float*)d_in[6];
  const float* Wo  = (const float*)d_in[7];
  const float* bo  = (const float*)d_in[8];
  const float* gc  = (const float*)d_in[9];
  const float* bc  = (const float*)d_in[10];
  const float* W1  = (const float*)d_in[11];
  const float* b1  = (const float*)d_in[12];
  const float* W2  = (const float*)d_in[13];
  const float* b2  = (const float*)d_in[14];
  float* out = (float*)d_out;

  char* ws = (char*)d_ws;
  size_t off = 0;
  auto bump = [&](size_t bytes) -> size_t {
    size_t o = off; off += (bytes + 255) & ~(size_t)255; return o;
  };
  const size_t act = (size_t)ROWSX * Cd * 2;
  size_t o_keep = bump(ROWSX);
  size_t o_xn   = bump(act);
  size_t o_x1n  = bump(act);
  size_t o_q    = bump(act);
  size_t o_ob   = bump(act);
  size_t o_x1   = bump(act);
  size_t o_hid  = bump((size_t)4096 * HIDn * 2);
  size_t o_wtq  = bump((size_t)Cd*Cd*2);
  size_t o_wtkv = bump((size_t)Cd*2*Cd*2);
  size_t o_wto  = bump((size_t)Cd*Cd*2);
  size_t o_wt1  = bump((size_t)Cd*HIDn*2);
  size_t o_wt2  = bump((size_t)HIDn*Cd*2);
  size_t o_cn   = bump((size_t)CBc * NCn * Cd * 2);
  size_t o_kv   = bump((size_t)CBc * NCn * 2 * Cd * 2);

  u8*  keep = (u8*)(ws + o_keep);
  u16* xn   = (u16*)(ws + o_xn);
  u16* x1n  = (u16*)(ws + o_x1n);
  u16* qb   = (u16*)(ws + o_q);
  u16* obuf = (u16*)(ws + o_ob);
  u16* x1b  = (u16*)(ws + o_x1);
  u16* hidb = (u16*)(ws + o_hid);
  u16* wtq  = (u16*)(ws + o_wtq);
  u16* wtkv = (u16*)(ws + o_wtkv);
  u16* wto  = (u16*)(ws + o_wto);
  u16* wt1  = (u16*)(ws + o_wt1);
  u16* wt2  = (u16*)(ws + o_wt2);
  u16* cnb  = (u16*)(ws + o_cn);
  u16* kvb  = (u16*)(ws + o_kv);

  decode_mask_kernel<<<1, 256, 0, stream>>>(msk, keep);

  wconvt_kernel<<<(Cd/64)*(Cd/64),     256, 0, stream>>>(Wq,  wtq,  Cd,   Cd);
  wconvt_kernel<<<(Cd/64)*(2*Cd/64),   256, 0, stream>>>(Wkv, wtkv, Cd,   2*Cd);
  wconvt_kernel<<<(Cd/64)*(Cd/64),     256, 0, stream>>>(Wo,  wto,  Cd,   Cd);
  wconvt_kernel<<<(Cd/64)*(HIDn/64),   256, 0, stream>>>(W1,  wt1,  Cd,   HIDn);
  wconvt_kernel<<<(HIDn/64)*(Cd/64),   256, 0, stream>>>(W2,  wt2,  HIDn, Cd);

  lnorm_kernel<0,1><<<ROWSX/4, 256, 0, stream>>>(x, nullptr, nullptr, xn, 1e-6f);

  // q = LN(x) @ Wq + bq
  mgemm_kernel<0,0,0,0><<<3*(ROWSX/128), 256, 0, stream>>>(
      xn, wtq, bq, nullptr, qb, ROWSX, Cd, Cd, 3);

  for (int b0 = 0; b0 < BTn; b0 += CBc) {
    lnorm_kernel<1,1><<<CBc*NCn/4, 256, 0, stream>>>(
        ctx + (size_t)b0*NCn*Cd, gc, bc, cnb, 1e-5f);
    mgemm_kernel<0,0,0,0><<<6*(CBc*NCn/128), 256, 0, stream>>>(
        cnb, wtkv, bkv, nullptr, kvb, CBc*NCn, 2*Cd, Cd, 6);
    fattn_kernel<<<dim3(Hn, CBc), 256, 0, stream>>>(qb, kvb, keep, obuf, b0);
  }

  // x1 = x + o @ Wo + bo
  mgemm_kernel<0,1,1,0><<<3*(ROWSX/128), 256, 0, stream>>>(
      obuf, wto, bo, x, x1b, ROWSX, Cd, Cd, 3);

  lnorm_kernel<0,0><<<ROWSX/4, 256, 0, stream>>>(x1b, nullptr, nullptr, x1n, 1e-6f);

  // MLP in 3 row-chunks of 4096
  for (int rc = 0; rc < 3; rc++) {
    const size_t r0 = (size_t)rc * 4096;
    mgemm_kernel<1,0,0,0><<<12*(4096/128), 256, 0, stream>>>(
        x1n + r0*Cd, wt1, b1, nullptr, hidb, 4096, HIDn, Cd, 12);
    mgemm_kernel<0,1,0,1><<<3*(4096/128), 256, 0, stream>>>(
        hidb, wt2, b2, x1b + r0*Cd, out + r0*Cd, 4096, Cd, HIDn, 3);
  }
}

// Round 7
// 574.203 us; speedup vs baseline: 6.5610x; 1.1625x over previous
//
#include <hip/hip_runtime.h>
#include <hip/hip_bf16.h>
#include <math.h>

typedef unsigned int  u32;
typedef unsigned short u16;
typedef unsigned char u8;

#define BTn   192
#define NQn   64
#define NCn   1024
#define Cd    384
#define Hn    8
#define DHn   48
#define HIDn  1536
#define ROWSX (BTn*NQn)     /* 12288 */
#define ROWSC (BTn*NCn)     /* 196608 */
#define ATT_SCALE 0.14433756729740643f
#define CBc   64            /* batch chunk: kvb+cnb = 151 MB, L3-resident */

typedef __bf16 bf16x8 __attribute__((ext_vector_type(8)));
typedef float  f32x4  __attribute__((ext_vector_type(4)));

#define GLL16(gp, lp) __builtin_amdgcn_global_load_lds( \
    (const __attribute__((address_space(1))) void*)(gp), \
    (__attribute__((address_space(3))) void*)(lp), 16, 0, 0)

__device__ __forceinline__ float bf2f(u32 u) {
  union { u32 i; float f; } v; v.i = u << 16; return v.f;
}
__device__ __forceinline__ u16 f2bf(float f) {
  union { float f; u32 i; } v; v.f = f;
  u32 x = v.i;
  x += 0x7fffu + ((x >> 16) & 1u);
  return (u16)(x >> 16);
}
__device__ __forceinline__ void decode8(uint4 r, float* v) {
  v[0]=bf2f(r.x & 0xffffu); v[1]=bf2f(r.x >> 16);
  v[2]=bf2f(r.y & 0xffffu); v[3]=bf2f(r.y >> 16);
  v[4]=bf2f(r.z & 0xffffu); v[5]=bf2f(r.z >> 16);
  v[6]=bf2f(r.w & 0xffffu); v[7]=bf2f(r.w >> 16);
}
__device__ __forceinline__ float gelu_f(float x) {
  float x3 = x*x*x;
  float z = 0.7978845608028654f*x + 0.035677408136300125f*x3;
  float e = __expf(2.f*z);
  float th = 1.f - 2.f/(e+1.f);
  return 0.5f*x*(1.f+th);
}

// ---------------- mask decode (robust to u8 / i32 / bf16 / f32 storage) ---
__global__ void decode_mask_kernel(const u8* __restrict__ m, u8* __restrict__ keep) {
  __shared__ int flags[3];
  int t = threadIdx.x;
  if (t < 3) flags[t] = 0;
  __syncthreads();
  int nonbin = 0, oddset = 0, low01 = 0;
  for (int i = t; i < ROWSX; i += 256) {
    u32 b = m[i];
    if (b > 1u) nonbin = 1;
    if ((i & 3) && b) oddset = 1;
    if (((i & 3) < 2) && b) low01 = 1;
  }
  if (nonbin) flags[0] = 1;
  if (oddset) flags[1] = 1;
  if (low01)  flags[2] = 1;
  __syncthreads();
  int mode = flags[0] ? (flags[2] ? 2 : 3) : (flags[1] ? 1 : 0);
  for (int i = t; i < ROWSX; i += 256) {
    u8 k;
    if (mode == 2)      k = (m[2*i] | m[2*i+1]) ? 1 : 0;
    else if (mode == 3) k = (((const float*)m)[i] != 0.f) ? 1 : 0;
    else if (mode == 1) k = m[i] ? 1 : 0;
    else                k = (((const int*)m)[i] != 0) ? 1 : 0;
    keep[i] = k;
  }
}

// ---------------- fused LayerNorm -> bf16 (wave per row) ------------------
template<int AFF, int SRCF32>
__global__ __launch_bounds__(256) void lnorm_kernel(
    const void* __restrict__ srcv, const float* __restrict__ gw,
    const float* __restrict__ bw, u16* __restrict__ dst, float eps)
{
  const int row  = blockIdx.x * 4 + (threadIdx.x >> 6);
  const int lane = threadIdx.x & 63;
  float v[6];
  if (SRCF32) {
    const float2* p = (const float2*)((const float*)srcv + (size_t)row*Cd);
    #pragma unroll
    for (int i = 0; i < 3; i++) { float2 u = p[lane + 64*i]; v[2*i]=u.x; v[2*i+1]=u.y; }
  } else {
    const u32* p = (const u32*)((const u16*)srcv + (size_t)row*Cd);
    #pragma unroll
    for (int i = 0; i < 3; i++) { u32 u = p[lane + 64*i]; v[2*i]=bf2f(u&0xffffu); v[2*i+1]=bf2f(u>>16); }
  }
  float s  = v[0]+v[1]+v[2]+v[3]+v[4]+v[5];
  float s2 = v[0]*v[0]+v[1]*v[1]+v[2]*v[2]+v[3]*v[3]+v[4]*v[4]+v[5]*v[5];
  #pragma unroll
  for (int o = 32; o >= 1; o >>= 1) { s += __shfl_xor(s, o); s2 += __shfl_xor(s2, o); }
  float mean = s * (1.0f/Cd);
  float var  = s2 * (1.0f/Cd) - mean*mean;
  var = var > 0.f ? var : 0.f;
  float rstd = rsqrtf(var + eps);
  u32* d32 = (u32*)(dst + (size_t)row*Cd);
  #pragma unroll
  for (int i = 0; i < 3; i++) {
    float y0 = (v[2*i]   - mean) * rstd;
    float y1 = (v[2*i+1] - mean) * rstd;
    if (AFF) {
      float2 gg = *(const float2*)(gw + 2*(lane + 64*i));
      float2 bb = *(const float2*)(bw + 2*(lane + 64*i));
      y0 = y0*gg.x + bb.x;
      y1 = y1*gg.y + bb.y;
    }
    d32[lane + 64*i] = (u32)f2bf(y0) | ((u32)f2bf(y1) << 16);
  }
}

// ------- batched weight transpose+convert: W[K][N] f32 -> WT[N][K] bf16 ---
struct WPack {
  const float* W[5];
  u16* WT[5];
  int K[5];
  int N[5];
  int off[6];
};
__global__ __launch_bounds__(256) void wconvt_all_kernel(WPack p) {
  __shared__ u16 tile[64][66];
  const int bid = blockIdx.x;
  int s = 0;
  #pragma unroll
  for (int i = 1; i < 5; i++) if (bid >= p.off[i]) s = i;
  const float* W = p.W[s];
  u16* WT = p.WT[s];
  const int K = p.K[s], N = p.N[s];
  const int lb = bid - p.off[s];
  const int t  = threadIdx.x;
  const int nt = N >> 6;
  const int bk = lb / nt, bn = lb % nt;
  const int q  = t >> 6;
  const int nl = t & 63;
  #pragma unroll
  for (int r = 0; r < 16; r++) {
    int k = q*16 + r;
    tile[nl][k] = f2bf(W[(size_t)(bk*64 + k)*N + bn*64 + nl]);
  }
  __syncthreads();
  #pragma unroll
  for (int r = 0; r < 16; r++) {
    int n = q*16 + r;
    WT[(size_t)(bn*64 + n)*K + bk*64 + nl] = tile[n][nl];
  }
}

// ---------------- MFMA GEMM 128x128 (4 waves): for N%128 tiles ------------
// 3-buffer LDS, depth-2 counted vmcnt, XOR swizzle, XCD-contiguous remap.
template<int GEL, int RES, int RF32, int OF32>
__global__ __launch_bounds__(256) void mgemm_kernel(
    const u16* __restrict__ A, const u16* __restrict__ WT,
    const float* __restrict__ bias, const void* __restrict__ resv,
    void* __restrict__ Coutv, int M, int N, int K, int nx)
{
  __shared__ u16 As[3][4096];
  __shared__ u16 Bs[3][4096];
  const int t = threadIdx.x;
  const int w = t >> 6, l = t & 63, l15 = l & 15, g = l >> 4;

  const int nwg = gridDim.x;
  const int bid = blockIdx.x;
  const int wg  = (bid & 7) * (nwg >> 3) + (bid >> 3);
  const int n0 = (wg % nx) * 128, m0 = (wg / nx) * 128;
  const int wm = (w & 1) * 64, wn = (w >> 1) * 64;

  const int arow = t >> 2;
  const int swk  = (t >> 3) & 3;
  const int acol = ((t & 3) ^ swk) * 8;
  const u16* Ag = A  + (size_t)(m0 + arow) * K + acol;
  const u16* Wg = WT + (size_t)(n0 + arow) * K + acol;
  const size_t rowskip = (size_t)64 * K;

  const int xk   = (l15 >> 1) & 3;
  const int goff = ((g ^ xk) << 3);

  f32x4 acc[4][4];
  #pragma unroll
  for (int i = 0; i < 4; i++)
    #pragma unroll
    for (int j = 0; j < 4; j++) acc[i][j] = (f32x4){0.f, 0.f, 0.f, 0.f};

  const int nIter = K >> 5;

#define STAGE(nb, kk) do { \
    GLL16(Ag + (kk),           &As[nb][t*8]); \
    GLL16(Ag + (kk) + rowskip, &As[nb][2048 + t*8]); \
    GLL16(Wg + (kk),           &Bs[nb][t*8]); \
    GLL16(Wg + (kk) + rowskip, &Bs[nb][2048 + t*8]); \
  } while (0)

#define BODY(BUF, IT) do { \
    const int it_ = (IT); \
    if (it_ + 2 < nIter) { \
      STAGE((BUF + 2) % 3, (it_ + 2) << 5); \
      asm volatile("s_waitcnt vmcnt(8)" ::: "memory"); \
    } else if (it_ + 1 < nIter) { \
      asm volatile("s_waitcnt vmcnt(4)" ::: "memory"); \
    } else { \
      asm volatile("s_waitcnt vmcnt(0)" ::: "memory"); \
    } \
    __builtin_amdgcn_s_barrier(); \
    __builtin_amdgcn_sched_barrier(0); \
    { \
      bf16x8 af[4], bfv[4]; \
      _Pragma("unroll") \
      for (int i = 0; i < 4; i++) \
        af[i] = *(const bf16x8*)&As[BUF][(wm + i*16 + l15)*32 + goff]; \
      _Pragma("unroll") \
      for (int j = 0; j < 4; j++) \
        bfv[j] = *(const bf16x8*)&Bs[BUF][(wn + j*16 + l15)*32 + goff]; \
      _Pragma("unroll") \
      for (int i = 0; i < 4; i++) \
        _Pragma("unroll") \
        for (int j = 0; j < 4; j++) \
          acc[i][j] = __builtin_amdgcn_mfma_f32_16x16x32_bf16(bfv[j], af[i], acc[i][j], 0, 0, 0); \
    } \
    __builtin_amdgcn_sched_barrier(0); \
    __builtin_amdgcn_s_barrier(); \
  } while (0)

  STAGE(0, 0);
  STAGE(1, 32);
  for (int it0 = 0; it0 < nIter; it0 += 3) {
    BODY(0, it0);
    BODY(1, it0 + 1);
    BODY(2, it0 + 2);
  }
#undef BODY
#undef STAGE

  const float* resf = (const float*)resv;
  const u16*   resb = (const u16*)resv;
  float* Cf = (float*)Coutv;
  u16*   Cb = (u16*)Coutv;
  #pragma unroll
  for (int j = 0; j < 4; j++) {
    const int nb = n0 + wn + j*16 + g*4;
    const float4 bv = *(const float4*)&bias[nb];
    #pragma unroll
    for (int i = 0; i < 4; i++) {
      const int m = m0 + wm + i*16 + l15;
      float c0 = acc[i][j][0] + bv.x;
      float c1 = acc[i][j][1] + bv.y;
      float c2 = acc[i][j][2] + bv.z;
      float c3 = acc[i][j][3] + bv.w;
      if (GEL) { c0 = gelu_f(c0); c1 = gelu_f(c1); c2 = gelu_f(c2); c3 = gelu_f(c3); }
      if (RES) {
        if (RF32) {
          float4 r = *(const float4*)&resf[(size_t)m*N + nb];
          c0 += r.x; c1 += r.y; c2 += r.z; c3 += r.w;
        } else {
          uint2 r = *(const uint2*)&resb[(size_t)m*N + nb];
          c0 += bf2f(r.x & 0xffffu); c1 += bf2f(r.x >> 16);
          c2 += bf2f(r.y & 0xffffu); c3 += bf2f(r.y >> 16);
        }
      }
      if (OF32) {
        *(float4*)&Cf[(size_t)m*N + nb] = make_float4(c0, c1, c2, c3);
      } else {
        uint2 pk = make_uint2((u32)f2bf(c0) | ((u32)f2bf(c1) << 16),
                              (u32)f2bf(c2) | ((u32)f2bf(c3) << 16));
        *(uint2*)&Cb[(size_t)m*N + nb] = pk;
      }
    }
  }
}

// ---------------- MFMA GEMM 128x256 (8 waves): for N%256 tiles ------------
// Same per-wave structure; BN=256 halves A-panel re-staging; 16 waves/CU.
template<int GEL, int RES, int RF32, int OF32>
__global__ __launch_bounds__(512, 4) void mgemm256_kernel(
    const u16* __restrict__ A, const u16* __restrict__ WT,
    const float* __restrict__ bias, const void* __restrict__ resv,
    void* __restrict__ Coutv, int M, int N, int K, int nx)
{
  __shared__ u16 As[3][4096];   // 128 x 32
  __shared__ u16 Bs[3][8192];   // 256 x 32
  const int t = threadIdx.x;                 // 0..511
  const int w = t >> 6, l = t & 63, l15 = l & 15, g = l >> 4;

  const int nwg = gridDim.x;
  const int bid = blockIdx.x;
  const int wg  = (bid & 7) * (nwg >> 3) + (bid >> 3);
  const int n0 = (wg % nx) * 256, m0 = (wg / nx) * 128;
  const int wm = (w & 1) * 64, wn = (w >> 1) * 64;   // wn 0..192

  const int arow = t >> 2;                   // 0..127
  const int swk  = (t >> 3) & 3;             // (arow>>1)&3 (also valid for arow+128)
  const int acol = ((t & 3) ^ swk) * 8;
  const u16* Ag = A  + (size_t)(m0 + arow) * K + acol;
  const u16* Wg = WT + (size_t)(n0 + arow) * K + acol;
  const size_t rowskipB = (size_t)128 * K;

  const int xk   = (l15 >> 1) & 3;
  const int goff = ((g ^ xk) << 3);

  f32x4 acc[4][4];
  #pragma unroll
  for (int i = 0; i < 4; i++)
    #pragma unroll
    for (int j = 0; j < 4; j++) acc[i][j] = (f32x4){0.f, 0.f, 0.f, 0.f};

  const int nIter = K >> 5;

#define STAGE(nb, kk) do { \
    GLL16(Ag + (kk),            &As[nb][t*8]); \
    GLL16(Wg + (kk),            &Bs[nb][t*8]); \
    GLL16(Wg + (kk) + rowskipB, &Bs[nb][4096 + t*8]); \
  } while (0)

#define BODY(BUF, IT) do { \
    const int it_ = (IT); \
    if (it_ + 2 < nIter) { \
      STAGE((BUF + 2) % 3, (it_ + 2) << 5); \
      asm volatile("s_waitcnt vmcnt(6)" ::: "memory"); \
    } else if (it_ + 1 < nIter) { \
      asm volatile("s_waitcnt vmcnt(3)" ::: "memory"); \
    } else { \
      asm volatile("s_waitcnt vmcnt(0)" ::: "memory"); \
    } \
    __builtin_amdgcn_s_barrier(); \
    __builtin_amdgcn_sched_barrier(0); \
    { \
      bf16x8 af[4], bfv[4]; \
      _Pragma("unroll") \
      for (int i = 0; i < 4; i++) \
        af[i] = *(const bf16x8*)&As[BUF][(wm + i*16 + l15)*32 + goff]; \
      _Pragma("unroll") \
      for (int j = 0; j < 4; j++) \
        bfv[j] = *(const bf16x8*)&Bs[BUF][(wn + j*16 + l15)*32 + goff]; \
      _Pragma("unroll") \
      for (int i = 0; i < 4; i++) \
        _Pragma("unroll") \
        for (int j = 0; j < 4; j++) \
          acc[i][j] = __builtin_amdgcn_mfma_f32_16x16x32_bf16(bfv[j], af[i], acc[i][j], 0, 0, 0); \
    } \
    __builtin_amdgcn_sched_barrier(0); \
    __builtin_amdgcn_s_barrier(); \
  } while (0)

  STAGE(0, 0);
  STAGE(1, 32);
  for (int it0 = 0; it0 < nIter; it0 += 3) {
    BODY(0, it0);
    BODY(1, it0 + 1);
    BODY(2, it0 + 2);
  }
#undef BODY
#undef STAGE

  const float* resf = (const float*)resv;
  const u16*   resb = (const u16*)resv;
  float* Cf = (float*)Coutv;
  u16*   Cb = (u16*)Coutv;
  #pragma unroll
  for (int j = 0; j < 4; j++) {
    const int nb = n0 + wn + j*16 + g*4;
    const float4 bv = *(const float4*)&bias[nb];
    #pragma unroll
    for (int i = 0; i < 4; i++) {
      const int m = m0 + wm + i*16 + l15;
      float c0 = acc[i][j][0] + bv.x;
      float c1 = acc[i][j][1] + bv.y;
      float c2 = acc[i][j][2] + bv.z;
      float c3 = acc[i][j][3] + bv.w;
      if (GEL) { c0 = gelu_f(c0); c1 = gelu_f(c1); c2 = gelu_f(c2); c3 = gelu_f(c3); }
      if (RES) {
        if (RF32) {
          float4 r = *(const float4*)&resf[(size_t)m*N + nb];
          c0 += r.x; c1 += r.y; c2 += r.z; c3 += r.w;
        } else {
          uint2 r = *(const uint2*)&resb[(size_t)m*N + nb];
          c0 += bf2f(r.x & 0xffffu); c1 += bf2f(r.x >> 16);
          c2 += bf2f(r.y & 0xffffu); c3 += bf2f(r.y >> 16);
        }
      }
      if (OF32) {
        *(float4*)&Cf[(size_t)m*N + nb] = make_float4(c0, c1, c2, c3);
      } else {
        uint2 pk = make_uint2((u32)f2bf(c0) | ((u32)f2bf(c1) << 16),
                              (u32)f2bf(c2) | ((u32)f2bf(c3) << 16));
        *(uint2*)&Cb[(size_t)m*N + nb] = pk;
      }
    }
  }
}

// ---------------- flash attention, MFMA, one block per (b,h) --------------
__global__ __launch_bounds__(256) void fattn_kernel(
    const u16* __restrict__ qb, const u16* __restrict__ kvb,
    const u8* __restrict__ keep, u16* __restrict__ ob, int b0)
{
  __shared__ u16 Qs[64*72];
  __shared__ u16 Ks[64*72];
  __shared__ u16 Vt[48*72];
  __shared__ u16 Ps[4][16*72];

  const int t = threadIdx.x;
  const int w = t >> 6, l = t & 63, l15 = l & 15, g = l >> 4;
  const int h = blockIdx.x, bz = blockIdx.y;
  const int b = b0 + bz;
  const int wq = w * 16;
  const int krow0 = t / 6, kp0 = t % 6;
  const int krow1 = (256 + t) / 6, kp1 = (256 + t) % 6;   // t<128
  const int vdq = (t >> 4) * 4, vkq = (t & 15) * 4;       // t<192

  for (int i = t; i < 2304; i += 256) { ((u32*)Qs)[i] = 0; ((u32*)Ks)[i] = 0; }
  __syncthreads();

  for (int i = t; i < 384; i += 256) {
    int row = i / 6, p = i % 6;
    uint4 v4 = *(const uint4*)(qb + (size_t)(b*NQn + row)*Cd + h*DHn + p*8);
    float f[8]; decode8(v4, f);
    u16 e[8];
    #pragma unroll
    for (int j = 0; j < 8; j++) e[j] = f2bf(f[j] * ATT_SCALE);
    uint4 pk = make_uint4((u32)e[0] | ((u32)e[1] << 16), (u32)e[2] | ((u32)e[3] << 16),
                          (u32)e[4] | ((u32)e[5] << 16), (u32)e[6] | ((u32)e[7] << 16));
    *(uint4*)&Qs[row*72 + p*8] = pk;
  }

  u32 kw = *(const u32*)&keep[b*NQn + wq + g*4];
  float kf[4];
  #pragma unroll
  for (int r = 0; r < 4; r++) kf[r] = ((kw >> (8*r)) & 0xffu) ? 1.f : 0.f;

  float mrow[4], lrow[4];
  f32x4 oacc[3];
  #pragma unroll
  for (int r = 0; r < 4; r++) { mrow[r] = -3.0e38f; lrow[r] = 0.f; }
  #pragma unroll
  for (int d = 0; d < 3; d++) oacc[d] = (f32x4){0.f, 0.f, 0.f, 0.f};

  auto loadKV = [&](int kt, uint4& KR0, uint4& KR1, uint2* V) {
    const u16* base = kvb + ((size_t)bz*NCn + (size_t)kt*64) * (2*(size_t)Cd);
    KR0 = *(const uint4*)(base + (size_t)krow0*(2*Cd) + h*DHn + kp0*8);
    if (t < 128)
      KR1 = *(const uint4*)(base + (size_t)krow1*(2*Cd) + h*DHn + kp1*8);
    if (t < 192) {
      const u16* vs = base + (size_t)vkq*(2*Cd) + Cd + h*DHn + vdq;
      V[0] = *(const uint2*)(vs);
      V[1] = *(const uint2*)(vs + 2*Cd);
      V[2] = *(const uint2*)(vs + 4*Cd);
      V[3] = *(const uint2*)(vs + 6*Cd);
    }
  };
  auto writeKV = [&](const uint4& KR0, const uint4& KR1, const uint2* V) {
    *(uint4*)&Ks[krow0*72 + kp0*8] = KR0;
    if (t < 128) *(uint4*)&Ks[krow1*72 + kp1*8] = KR1;
    if (t < 192) {
      #pragma unroll
      for (int jj = 0; jj < 4; jj++) {
        u16 o4[4] = {((const u16*)&V[0])[jj], ((const u16*)&V[1])[jj],
                     ((const u16*)&V[2])[jj], ((const u16*)&V[3])[jj]};
        *(uint2*)&Vt[(vdq+jj)*72 + vkq] = *(uint2*)o4;
      }
    }
  };

  bf16x8 qf0, qf1;
  auto compute = [&]() {
    f32x4 sf[4];
    #pragma unroll
    for (int f = 0; f < 4; f++) {
      bf16x8 ka = *(const bf16x8*)&Ks[(f*16 + l15)*72 + g*8];
      bf16x8 kb = *(const bf16x8*)&Ks[(f*16 + l15)*72 + 32 + g*8];
      f32x4 z = (f32x4){0.f, 0.f, 0.f, 0.f};
      z = __builtin_amdgcn_mfma_f32_16x16x32_bf16(qf0, ka, z, 0, 0, 0);
      sf[f] = __builtin_amdgcn_mfma_f32_16x16x32_bf16(qf1, kb, z, 0, 0, 0);
    }
    float p[4][4], sc_[4];
    #pragma unroll
    for (int r = 0; r < 4; r++) {
      float pmax = fmaxf(fmaxf(sf[0][r], sf[1][r]), fmaxf(sf[2][r], sf[3][r]));
      #pragma unroll
      for (int s = 1; s < 16; s <<= 1) pmax = fmaxf(pmax, __shfl_xor(pmax, s));
      float mn = kf[r] > 0.f ? fmaxf(mrow[r], pmax) : 0.f;
      sc_[r] = kf[r] > 0.f ? __expf(mrow[r] - mn) : 1.f;
      mrow[r] = mn;
      float p0 = kf[r] > 0.f ? __expf(sf[0][r] - mn) : 1.f;
      float p1 = kf[r] > 0.f ? __expf(sf[1][r] - mn) : 1.f;
      float p2 = kf[r] > 0.f ? __expf(sf[2][r] - mn) : 1.f;
      float p3 = kf[r] > 0.f ? __expf(sf[3][r] - mn) : 1.f;
      p[0][r]=p0; p[1][r]=p1; p[2][r]=p2; p[3][r]=p3;
      float ps = p0+p1+p2+p3;
      #pragma unroll
      for (int s = 1; s < 16; s <<= 1) ps += __shfl_xor(ps, s);
      lrow[r] = lrow[r]*sc_[r] + ps;
      oacc[0][r] *= sc_[r]; oacc[1][r] *= sc_[r]; oacc[2][r] *= sc_[r];
    }
    #pragma unroll
    for (int f = 0; f < 4; f++)
      #pragma unroll
      for (int r = 0; r < 4; r++)
        Ps[w][(g*4 + r)*72 + f*16 + l15] = f2bf(p[f][r]);
    bf16x8 pa0 = *(const bf16x8*)&Ps[w][l15*72 + g*8];
    bf16x8 pa1 = *(const bf16x8*)&Ps[w][l15*72 + 32 + g*8];
    #pragma unroll
    for (int df = 0; df < 3; df++) {
      bf16x8 vb0 = *(const bf16x8*)&Vt[(df*16 + l15)*72 + g*8];
      bf16x8 vb1 = *(const bf16x8*)&Vt[(df*16 + l15)*72 + 32 + g*8];
      oacc[df] = __builtin_amdgcn_mfma_f32_16x16x32_bf16(pa0, vb0, oacc[df], 0, 0, 0);
      oacc[df] = __builtin_amdgcn_mfma_f32_16x16x32_bf16(pa1, vb1, oacc[df], 0, 0, 0);
    }
  };

  uint4 ka0, ka1, kb0_, kb1_;
  uint2 va[4], vb_[4];
  loadKV(0, ka0, ka1, va);
  __syncthreads();

  qf0 = *(const bf16x8*)&Qs[(wq + l15)*72 + g*8];
  qf1 = *(const bf16x8*)&Qs[(wq + l15)*72 + 32 + g*8];

  for (int kt = 0; kt < 16; kt += 2) {
    writeKV(ka0, ka1, va);
    asm volatile("s_waitcnt lgkmcnt(0)" ::: "memory");
    __builtin_amdgcn_sched_barrier(0);
    __builtin_amdgcn_s_barrier();
    __builtin_amdgcn_sched_barrier(0);
    loadKV(kt + 1, kb0_, kb1_, vb_);
    compute();
    __builtin_amdgcn_sched_barrier(0);
    __builtin_amdgcn_s_barrier();
    writeKV(kb0_, kb1_, vb_);
    asm volatile("s_waitcnt lgkmcnt(0)" ::: "memory");
    __builtin_amdgcn_sched_barrier(0);
    __builtin_amdgcn_s_barrier();
    __builtin_amdgcn_sched_barrier(0);
    if (kt + 2 < 16) loadKV(kt + 2, ka0, ka1, va);
    compute();
    if (kt + 2 < 16) {
      __builtin_amdgcn_sched_barrier(0);
      __builtin_amdgcn_s_barrier();
    }
  }

  #pragma unroll
  for (int r = 0; r < 4; r++) {
    float inv = 1.f / lrow[r];
    size_t qrow = (size_t)(b*NQn + wq + g*4 + r);
    #pragma unroll
    for (int df = 0; df < 3; df++)
      ob[qrow*Cd + h*DHn + df*16 + l15] = f2bf(oacc[df][r] * inv);
  }
}

// --------------------------------------------------------------------------
extern "C" void kernel_launch(void* const* d_in, const int* in_sizes, int n_in,
                              void* d_out, int out_size, void* d_ws, size_t ws_size,
                              hipStream_t stream) {
  (void)in_sizes; (void)n_in; (void)out_size; (void)ws_size;
  const float* x   = (const float*)d_in[0];
  const float* ctx = (const float*)d_in[1];
  const u8*    msk = (const u8*)   d_in[2];
  const float* Wq  = (const float*)d_in[3];
  const float* bq  = (const float*)d_in[4];
  const float* Wkv = (const float*)d_in[5];
  const float* bkv = (const float*)d_in[6];
  const float* Wo  = (const float*)d_in[7];
  const float* bo  = (const float*)d_in[8];
  const float* gc  = (const float*)d_in[9];
  const float* bc  = (const float*)d_in[10];
  const float* W1  = (const float*)d_in[11];
  const float* b1  = (const float*)d_in[12];
  const float* W2  = (const float*)d_in[13];
  const float* b2  = (const float*)d_in[14];
  float* out = (float*)d_out;

  char* ws = (char*)d_ws;
  size_t off = 0;
  auto bump = [&](size_t bytes) -> size_t {
    size_t o = off; off += (bytes + 255) & ~(size_t)255; return o;
  };
  const size_t act = (size_t)ROWSX * Cd * 2;
  size_t o_keep = bump(ROWSX);
  size_t o_xn   = bump(act);
  size_t o_x1n  = bump(act);
  size_t o_q    = bump(act);
  size_t o_ob   = bump(act);
  size_t o_x1   = bump(act);
  size_t o_hid  = bump((size_t)ROWSX * HIDn * 2);
  size_t o_wtq  = bump((size_t)Cd*Cd*2);
  size_t o_wtkv = bump((size_t)Cd*2*Cd*2);
  size_t o_wto  = bump((size_t)Cd*Cd*2);
  size_t o_wt1  = bump((size_t)Cd*HIDn*2);
  size_t o_wt2  = bump((size_t)HIDn*Cd*2);
  size_t o_cn   = bump((size_t)CBc * NCn * Cd * 2);
  size_t o_kv   = bump((size_t)CBc * NCn * 2 * Cd * 2);

  u8*  keep = (u8*)(ws + o_keep);
  u16* xn   = (u16*)(ws + o_xn);
  u16* x1n  = (u16*)(ws + o_x1n);
  u16* qb   = (u16*)(ws + o_q);
  u16* obuf = (u16*)(ws + o_ob);
  u16* x1b  = (u16*)(ws + o_x1);
  u16* hidb = (u16*)(ws + o_hid);
  u16* wtq  = (u16*)(ws + o_wtq);
  u16* wtkv = (u16*)(ws + o_wtkv);
  u16* wto  = (u16*)(ws + o_wto);
  u16* wt1  = (u16*)(ws + o_wt1);
  u16* wt2  = (u16*)(ws + o_wt2);
  u16* cnb  = (u16*)(ws + o_cn);
  u16* kvb  = (u16*)(ws + o_kv);

  decode_mask_kernel<<<1, 256, 0, stream>>>(msk, keep);

  // batched weight transpose: Wq(36), Wkv(72), Wo(36), W1(144), W2(144)
  WPack wp;
  wp.W[0]=Wq;  wp.WT[0]=wtq;  wp.K[0]=Cd;   wp.N[0]=Cd;
  wp.W[1]=Wkv; wp.WT[1]=wtkv; wp.K[1]=Cd;   wp.N[1]=2*Cd;
  wp.W[2]=Wo;  wp.WT[2]=wto;  wp.K[2]=Cd;   wp.N[2]=Cd;
  wp.W[3]=W1;  wp.WT[3]=wt1;  wp.K[3]=Cd;   wp.N[3]=HIDn;
  wp.W[4]=W2;  wp.WT[4]=wt2;  wp.K[4]=HIDn; wp.N[4]=Cd;
  wp.off[0]=0; wp.off[1]=36; wp.off[2]=108; wp.off[3]=144; wp.off[4]=288; wp.off[5]=432;
  wconvt_all_kernel<<<432, 256, 0, stream>>>(wp);

  lnorm_kernel<0,1><<<ROWSX/4, 256, 0, stream>>>(x, nullptr, nullptr, xn, 1e-6f);

  // q = LN(x) @ Wq + bq
  mgemm_kernel<0,0,0,0><<<3*(ROWSX/128), 256, 0, stream>>>(
      xn, wtq, bq, nullptr, qb, ROWSX, Cd, Cd, 3);

  for (int b0 = 0; b0 < BTn; b0 += CBc) {
    lnorm_kernel<1,1><<<CBc*NCn/4, 256, 0, stream>>>(
        ctx + (size_t)b0*NCn*Cd, gc, bc, cnb, 1e-5f);
    mgemm256_kernel<0,0,0,0><<<3*(CBc*NCn/128), 512, 0, stream>>>(
        cnb, wtkv, bkv, nullptr, kvb, CBc*NCn, 2*Cd, Cd, 3);
    fattn_kernel<<<dim3(Hn, CBc), 256, 0, stream>>>(qb, kvb, keep, obuf, b0);
  }

  // x1 = x + o @ Wo + bo
  mgemm_kernel<0,1,1,0><<<3*(ROWSX/128), 256, 0, stream>>>(
      obuf, wto, bo, x, x1b, ROWSX, Cd, Cd, 3);

  lnorm_kernel<0,0><<<ROWSX/4, 256, 0, stream>>>(x1b, nullptr, nullptr, x1n, 1e-6f);

  // hidden = gelu(LN(x1) @ W1 + b1)   (full M, 128x256 tiles)
  mgemm256_kernel<1,0,0,0><<<6*(ROWSX/128), 512, 0, stream>>>(
      x1n, wt1, b1, nullptr, hidb, ROWSX, HIDn, Cd, 6);

  // out = x1 + hidden @ W2 + b2       (full M, 128x128 tiles)
  mgemm_kernel<0,1,0,1><<<3*(ROWSX/128), 256, 0, stream>>>(
      hidb, wt2, b2, x1b, out, ROWSX, Cd, HIDn, 3);
}